// Round 4
// baseline (170.984 us; speedup 1.0000x reference)
//
#include <hip/hip_runtime.h>
#include <hip/hip_bf16.h>

#define NN 7936
#define EE 63488
#define CIN 5
#define WW 64
#define KK 8
#define H1C 64
#define H2C 16
#define T1 57            // 64-8+1
#define T2 50            // 57-8+1
#define FT (T1*H2C)      // 912 elems per node for xt (f16)

typedef _Float16 half8 __attribute__((ext_vector_type(8)));
typedef _Float16 half4 __attribute__((ext_vector_type(4)));
typedef float f32x4 __attribute__((ext_vector_type(4)));

// ---------------------------------------------------------------------------
__global__ void k_detect(const int* __restrict__ ei, int* __restrict__ flag) {
    if (threadIdx.x == 0 && blockIdx.x == 0) {
        int f = 1;
        for (int i = 0; i < 32; ++i) {
            if (ei[2 * i + 1] != 0) { f = 0; break; }
        }
        *flag = f;
    }
}

__device__ __forceinline__ int load_row(const int* ei, int f, int e) {
    return f ? ei[2 * e] : ei[e];
}
__device__ __forceinline__ int load_col(const int* ei, int f, int e) {
    return f ? ei[2 * (EE + e)] : ei[EE + e];
}

// ---------------------------------------------------------------------------
// Fused: per-destination degree atomics (blocks 0..247) + weight prep
// (blocks 248..347).
__global__ void k_deg_prep(const int* __restrict__ ei, const int* __restrict__ flag,
                           const float* __restrict__ ew,
                           float* __restrict__ deg, int* __restrict__ cnt,
                           const float* __restrict__ Wc2, _Float16* __restrict__ w2p,
                           const float* __restrict__ Wc1, _Float16* __restrict__ w1p,
                           const float* __restrict__ Wg, _Float16* __restrict__ wgp) {
    int b = blockIdx.x;
    if (b < EE / 256) {
        int e = b * 256 + threadIdx.x;
        int f = *flag;
        int c = load_col(ei, f, e);
        atomicAdd(&deg[c], ew[e]);
        atomicAdd(&cnt[c], 1);
        return;
    }
    int i = (b - EE / 256) * 256 + threadIdx.x;
    if (i < 16384) {
        // conv2 B-frags: slot=(s*4+lg)*128+nt*16+c, elem e
        int e = i & 7;
        int slot = i >> 3;
        int c  = slot & 15;
        int nt = (slot >> 4) & 7;
        int g  = (slot >> 7) & 3;
        int s  = (slot >> 9) & 3;
        int ci = g * 4 + (e >> 1);
        w2p[i] = (_Float16)Wc2[(nt * 16 + c) * 128 + ci * 8 + 2 * s + (e & 1)];
    } else if (i < 16384 + 8192) {
        // conv1 GEMM1 A-frags with sigma channel permutation
        int j = i - 16384;
        int e = j & 7;
        int m = (j >> 3) & 127;
        int slg = j >> 10;              // 0..7 = s*4+lg
        int ci = (slg >> 2) * 4 + (slg & 3);
        int hi = m >> 6;                // 0 = P, 1 = Q
        int mb = m & 63;
        int mt = mb >> 4, r = mb & 15;
        int sig = hi * 64 + 32 * (mt >> 1) + 8 * (r >> 2) + 4 * (mt & 1) + (r & 3);
        w1p[j] = (ci < CIN) ? (_Float16)Wc1[sig * (CIN * KK) + ci * KK + e]
                            : (_Float16)0.0f;
    } else if (i < 16384 + 8192 + 1024) {
        // conv1 GEMM2 B-frags (Wg)
        int j = i - 16384 - 8192;
        int e = j & 7;
        int f = (j >> 3) & 15;
        int slg = j >> 7;               // 0..7
        int c = (slg >> 2) * 32 + (slg & 3) * 8 + e;
        wgp[j] = (_Float16)Wg[c * H2C + f];
    }
}

__global__ void k_scan(const int* __restrict__ cnt, int* __restrict__ offs,
                       int* __restrict__ cursor) {
    __shared__ int part[1024];
    int tid = threadIdx.x;
    int base = tid * 8;
    int local[8];
    int s = 0;
#pragma unroll
    for (int j = 0; j < 8; ++j) {
        int idx = base + j;
        int v = (idx < NN) ? cnt[idx] : 0;
        local[j] = s;
        s += v;
    }
    part[tid] = s;
    __syncthreads();
    for (int d = 1; d < 1024; d <<= 1) {
        int v = 0;
        if (tid >= d) v = part[tid - d];
        __syncthreads();
        if (tid >= d) part[tid] += v;
        __syncthreads();
    }
    int ex = (tid > 0) ? part[tid - 1] : 0;
#pragma unroll
    for (int j = 0; j < 8; ++j) {
        int idx = base + j;
        if (idx < NN) {
            offs[idx] = ex + local[j];
            cursor[idx] = ex + local[j];
        }
    }
    if (tid == 1023) offs[NN] = part[1023];
}

// ---------------------------------------------------------------------------
// Merged kernel: blocks [0, NN/4) run conv1 (register-resident, wave = node);
// blocks [NN/4, NN/4+EE/256) run the edge bucket-fill.
__global__ __launch_bounds__(256, 3) void k_conv1_fill(
        const float* __restrict__ x, const _Float16* __restrict__ w1p,
        const float* __restrict__ b1, const _Float16* __restrict__ wgp,
        _Float16* __restrict__ xt,
        const int* __restrict__ ei, const int* __restrict__ flag,
        const float* __restrict__ ew, const float* __restrict__ deg,
        int* __restrict__ cursor, int2* __restrict__ em) {
    if (blockIdx.x >= NN / 4) {
        // ---- bucket fill: em[pos] = (src, dinv[src]*ew) ----
        int e = (blockIdx.x - NN / 4) * 256 + threadIdx.x;
        if (e < EE) {
            int f = *flag;
            int c = load_col(ei, f, e);
            int r = load_row(ei, f, e);
            int pos = atomicAdd(&cursor[c], 1);
            em[pos] = make_int2(r, __float_as_int(rsqrtf(deg[r] + 1.0f) * ew[e]));
        }
        return;
    }
    // ---- conv1, fully register-resident (zero LDS, zero barriers) ----
    int tid = threadIdx.x;
    int w = tid >> 6, lane = tid & 63;
    int lc = lane & 15, lg = lane >> 4;
    int n = blockIdx.x * 4 + w;
    const float* xg = x + (size_t)n * (CIN * WW);

    const half8* w1v = (const half8*)w1p;
    const half8* wgv = (const half8*)wgp;

    half8 av[2][8];
#pragma unroll
    for (int s = 0; s < 2; ++s)
#pragma unroll
        for (int mt = 0; mt < 8; ++mt)
            av[s][mt] = w1v[(s * 4 + lg) * 128 + mt * 16 + lc];
    half8 bw[2];
#pragma unroll
    for (int s2 = 0; s2 < 2; ++s2) bw[s2] = wgv[(s2 * 4 + lg) * 16 + lc];

    const float* xr0 = xg + (size_t)lg * WW;
    const float* xr1 = xg + (size_t)(4 + lg) * WW;
    bool cok1 = (4 + lg) < CIN;

    f32x4 acc2[4];
#pragma unroll
    for (int mt2 = 0; mt2 < 4; ++mt2) acc2[mt2] = (f32x4)0.0f;

#pragma unroll
    for (int nt = 0; nt < 4; ++nt) {
        int t = nt * 16 + lc;
        half8 bf0, bf1;
#pragma unroll
        for (int e = 0; e < 8; ++e) {
            int tp = t + e;
            bf0[e] = (_Float16)((tp < WW) ? xr0[tp] : 0.0f);
            bf1[e] = (_Float16)((cok1 && tp < WW) ? xr1[tp] : 0.0f);
        }
        f32x4 acc[8];
#pragma unroll
        for (int mt = 0; mt < 8; ++mt) acc[mt] = (f32x4)0.0f;
#pragma unroll
        for (int mt = 0; mt < 8; ++mt)
            acc[mt] = __builtin_amdgcn_mfma_f32_16x16x32_f16(av[0][mt], bf0,
                                                             acc[mt], 0, 0, 0);
#pragma unroll
        for (int mt = 0; mt < 8; ++mt)
            acc[mt] = __builtin_amdgcn_mfma_f32_16x16x32_f16(av[1][mt], bf1,
                                                             acc[mt], 0, 0, 0);
        half4 h4[4];
#pragma unroll
        for (int mtp = 0; mtp < 4; ++mtp) {
            int cb = 32 * (mtp >> 1) + 8 * lg + 4 * (mtp & 1);
            float4 bP = *(const float4*)(b1 + cb);
            float4 bQ = *(const float4*)(b1 + 64 + cb);
            f32x4 P = acc[mtp];
            f32x4 Q = acc[mtp + 4];
            half4 hh;
            hh[0] = (_Float16)((P[0] + bP.x) * (1.0f / (1.0f + __expf(-(Q[0] + bQ.x)))));
            hh[1] = (_Float16)((P[1] + bP.y) * (1.0f / (1.0f + __expf(-(Q[1] + bQ.y)))));
            hh[2] = (_Float16)((P[2] + bP.z) * (1.0f / (1.0f + __expf(-(Q[2] + bQ.z)))));
            hh[3] = (_Float16)((P[3] + bP.w) * (1.0f / (1.0f + __expf(-(Q[3] + bQ.w)))));
            h4[mtp] = hh;
        }
#pragma unroll
        for (int s2 = 0; s2 < 2; ++s2) {
            half8 af = __builtin_shufflevector(h4[2 * s2], h4[2 * s2 + 1],
                                               0, 1, 2, 3, 4, 5, 6, 7);
            acc2[nt] = __builtin_amdgcn_mfma_f32_16x16x32_f16(af, bw[s2],
                                                              acc2[nt], 0, 0, 0);
        }
    }

    _Float16* xtn = xt + (size_t)n * FT;
#pragma unroll
    for (int mt2 = 0; mt2 < 4; ++mt2) {
#pragma unroll
        for (int j = 0; j < 4; ++j) {
            int t = mt2 * 16 + 4 * lg + j;
            if (t < T1) xtn[t * 16 + lc] = (_Float16)acc2[mt2][j];
        }
    }
}

// ---------------------------------------------------------------------------
// Fused gather + conv2. Wave = 1 node (r1 structure, proven best).
// Gather: 4-entry NAMED row ring (R0..R3, static register names — no runtime
// indexing, no scratch), unroll-by-4 chunks -> 4 neighbor rows in flight per
// wave (vs 1 in r1: the latency fix). em prefetched 4 ahead via plain
// broadcast loads. Out-of-range edges are ZERO-WEIGHT PADDED (read self row,
// L1-hot, wv=0) -> no compute-path branches at all.
// LDS: single 3200B wave-private region time-shared between gs (f16 [16][58],
// conv2 A-operand) and gout (f32 write staging) — overlay proven in r2.
// Writeback: LDS-staged coalesced NONTEMPORAL stores (r1 scheme: keeps the
// write stream out of L2 so xt stays resident -> FETCH 102 vs 154MB).
__global__ __launch_bounds__(256, 4) void k_gc2(
        const _Float16* __restrict__ xt, const float* __restrict__ deg,
        const int* __restrict__ offs, const int2* __restrict__ em,
        const float* __restrict__ bg, const _Float16* __restrict__ w2p,
        const float* __restrict__ b2, float* __restrict__ out) {
    __shared__ __align__(16) float smem[4][800];   // 3200 B per wave
    int tid = threadIdx.x;
    int w = tid >> 6, lane = tid & 63;
    int lc = lane & 15, lg = lane >> 4;
    int n = blockIdx.x * 4 + w;
    bool hi = lane < 50;                // second half8 covers elems 512..911

    float dc = rsqrtf(deg[n] + 1.0f);
    float a0[8], a1[8];
    {
        const half8* xs = (const half8*)(xt + (size_t)n * FT);
        half8 u0 = xs[lane];
        half8 u1 = (half8)(_Float16)0.0f;
        if (hi) u1 = xs[64 + lane];
        float sw = dc * dc;
#pragma unroll
        for (int j = 0; j < 8; ++j) {
            a0[j] = (float)u0[j] * sw;
            a1[j] = (float)u1[j] * sw;
        }
    }
    int beg = offs[n];
    int m = offs[n + 1] - beg;

    // LDEM: wave-uniform guard; pad entries read the self row with weight 0.
#define LDEM(K) (((K) < m) ? em[beg + (K)] : make_int2(n, 0))
#define LDROW(EK, PA, PB, WK) {                                                \
        WK = __int_as_float(EK.y) * dc;                                        \
        const half8* xr = (const half8*)(xt + (size_t)EK.x * FT);              \
        PA = xr[lane];                                                         \
        PB = (half8)(_Float16)0.0f;                                            \
        if (hi) PB = xr[64 + lane]; }
#define ACC(PA, PB, WK) { _Pragma("unroll")                                    \
    for (int j = 0; j < 8; ++j) { a0[j] += (float)PA[j] * WK;                  \
                                  a1[j] += (float)PB[j] * WK; } }

    half8 R0a, R0b, R1a, R1b, R2a, R2b, R3a, R3b;
    float W0, W1, W2, W3;
    int2 E0, E1, E2, E3;
    {
        int2 e0 = LDEM(0), e1 = LDEM(1), e2 = LDEM(2), e3 = LDEM(3);
        LDROW(e0, R0a, R0b, W0)
        LDROW(e1, R1a, R1b, W1)
        LDROW(e2, R2a, R2b, W2)
        LDROW(e3, R3a, R3b, W3)
    }
    E0 = LDEM(4); E1 = LDEM(5); E2 = LDEM(6); E3 = LDEM(7);

    for (int i = 0; i < m; i += 4) {
        ACC(R0a, R0b, W0) LDROW(E0, R0a, R0b, W0) E0 = LDEM(i + 8);
        ACC(R1a, R1b, W1) LDROW(E1, R1a, R1b, W1) E1 = LDEM(i + 9);
        ACC(R2a, R2b, W2) LDROW(E2, R2a, R2b, W2) E2 = LDEM(i + 10);
        ACC(R3a, R3b, W3) LDROW(E3, R3a, R3b, W3) E3 = LDEM(i + 11);
    }
#undef ACC
#undef LDROW
#undef LDEM

    // relu + bias -> gs[f][t] (f16, stride 58). Lane owns f=(lane&1)*8+j,
    // t = lane>>1 (a0) and 32+(lane>>1) (a1, lanes<50).
    {
        _Float16* g = (_Float16*)smem[w];
        int f0 = (lane & 1) * 8;
        int t0 = lane >> 1;
        float4 bgA = *(const float4*)(bg + f0);
        float4 bgB = *(const float4*)(bg + f0 + 4);
        float bv[8] = {bgA.x, bgA.y, bgA.z, bgA.w, bgB.x, bgB.y, bgB.z, bgB.w};
#pragma unroll
        for (int j = 0; j < 8; ++j) {
            g[(f0 + j) * 58 + t0] = (_Float16)fmaxf(a0[j] + bv[j], 0.0f);
            if (hi) g[(f0 + j) * 58 + 32 + t0] = (_Float16)fmaxf(a1[j] + bv[j], 0.0f);
        }
    }
    // wave-private LDS region: compiler orders write->read via lgkmcnt,
    // no __syncthreads needed (waves fully independent).

    const _Float16* g = (const _Float16*)smem[w];
    half8 af[4][4];
#pragma unroll
    for (int s = 0; s < 4; ++s)
#pragma unroll
        for (int mt = 0; mt < 4; ++mt) {
            int tb = mt * 16 + lc + 2 * s;
            half8 v;
#pragma unroll
            for (int j = 0; j < 4; ++j) {
                int ci = lg * 4 + j;
                v[2 * j]     = g[ci * 58 + tb];
                v[2 * j + 1] = g[ci * 58 + tb + 1];
            }
            af[s][mt] = v;
        }

    const half8* wsv = (const half8*)w2p;
    float* outn = out + (size_t)n * (H1C * T2);
    float* go = smem[w];
#pragma unroll
    for (int ntp = 0; ntp < 4; ++ntp) {
        f32x4 aP[4], aQ[4];
#pragma unroll
        for (int mt = 0; mt < 4; ++mt) { aP[mt] = (f32x4)0.0f; aQ[mt] = (f32x4)0.0f; }
#pragma unroll
        for (int s = 0; s < 4; ++s) {
            half8 bP = wsv[(s * 4 + lg) * 128 + ntp * 16 + lc];
            half8 bQ = wsv[(s * 4 + lg) * 128 + (ntp + 4) * 16 + lc];
#pragma unroll
            for (int mt = 0; mt < 4; ++mt) {
                aP[mt] = __builtin_amdgcn_mfma_f32_16x16x32_f16(af[s][mt], bP,
                                                                aP[mt], 0, 0, 0);
                aQ[mt] = __builtin_amdgcn_mfma_f32_16x16x32_f16(af[s][mt], bQ,
                                                                aQ[mt], 0, 0, 0);
            }
        }
        int c = ntp * 16 + lc;
        float bp = b2[c], bq = b2[64 + c];
        // stage [lc][t<50] into wave-private LDS (column-major rows of 50)
#pragma unroll
        for (int mt = 0; mt < 4; ++mt) {
#pragma unroll
            for (int e2 = 0; e2 < 4; ++e2) {
                int t = mt * 16 + lg * 4 + e2;
                if (t < T2) {
                    float vv = (aP[mt][e2] + bp) *
                               (1.0f / (1.0f + __expf(-(aQ[mt][e2] + bq))));
                    go[lc * T2 + t] = vv;
                }
            }
        }
        // coalesced nontemporal writeback: 800 floats = 3x1024B + 128B
        float* dst = outn + ntp * (16 * T2);
#pragma unroll
        for (int i = 0; i < 3; ++i) {
            f32x4 v = *(const f32x4*)(go + i * 256 + lane * 4);
            __builtin_nontemporal_store(v, (f32x4*)(dst + i * 256 + lane * 4));
        }
        if (lane < 8) {
            f32x4 v = *(const f32x4*)(go + 768 + lane * 4);
            __builtin_nontemporal_store(v, (f32x4*)(dst + 768 + lane * 4));
        }
    }
}

// ---------------------------------------------------------------------------
extern "C" void kernel_launch(void* const* d_in, const int* in_sizes, int n_in,
                              void* d_out, int out_size, void* d_ws, size_t ws_size,
                              hipStream_t stream) {
    const float* x   = (const float*)d_in[0];
    const int*   ei  = (const int*)d_in[1];
    const float* ea  = (const float*)d_in[2];
    const float* Wc1 = (const float*)d_in[4];
    const float* b1  = (const float*)d_in[5];
    const float* Wg  = (const float*)d_in[6];
    const float* bg  = (const float*)d_in[7];
    const float* Wc2 = (const float*)d_in[8];
    const float* b2  = (const float*)d_in[9];
    float* out = (float*)d_out;

    char* ws = (char*)d_ws;
    size_t off = 0;
    auto alloc = [&](size_t bytes) -> void* {
        void* p = ws + off;
        off += (bytes + 255) & ~(size_t)255;
        return p;
    };
    int*      flag   = (int*)alloc(4);
    float*    deg    = (float*)alloc((size_t)NN * 4);
    int*      cnt    = (int*)alloc((size_t)NN * 4);
    int*      offs   = (int*)alloc((size_t)(NN + 1) * 4);
    int*      cursor = (int*)alloc((size_t)NN * 4);
    int2*     em     = (int2*)alloc((size_t)EE * 8);
    _Float16* xt     = (_Float16*)alloc((size_t)NN * FT * 2);
    _Float16* w2p    = (_Float16*)alloc((size_t)16384 * 2);
    _Float16* w1p    = (_Float16*)alloc((size_t)8192 * 2);
    _Float16* wgp    = (_Float16*)alloc((size_t)1024 * 2);
    (void)ws_size; (void)in_sizes; (void)n_in; (void)out_size;

    hipMemsetAsync(deg, 0, (size_t)NN * 4, stream);
    hipMemsetAsync(cnt, 0, (size_t)NN * 4, stream);
    k_detect<<<1, 64, 0, stream>>>(ei, flag);
    k_deg_prep<<<EE / 256 + 100, 256, 0, stream>>>(ei, flag, ea, deg, cnt,
                                                   Wc2, w2p, Wc1, w1p, Wg, wgp);
    k_scan<<<1, 1024, 0, stream>>>(cnt, offs, cursor);
    k_conv1_fill<<<NN / 4 + EE / 256, 256, 0, stream>>>(x, w1p, b1, wgp, xt,
                                                        ei, flag, ea, deg,
                                                        cursor, em);
    k_gc2<<<NN / 4, 256, 0, stream>>>(xt, deg, offs, em, bg, w2p, b2, out);
}

// Round 5
// 164.485 us; speedup vs baseline: 1.0395x; 1.0395x over previous
//
#include <hip/hip_runtime.h>
#include <hip/hip_bf16.h>

#define NN 7936
#define EE 63488
#define CIN 5
#define WW 64
#define KK 8
#define H1C 64
#define H2C 16
#define T1 57            // 64-8+1
#define T2 50            // 57-8+1
#define FT (T1*H2C)      // 912 elems per node for xt (f16)

typedef _Float16 half8 __attribute__((ext_vector_type(8)));
typedef _Float16 half4 __attribute__((ext_vector_type(4)));
typedef float f32x4 __attribute__((ext_vector_type(4)));
typedef int i32x4 __attribute__((ext_vector_type(4)));

#define AS1 __attribute__((address_space(1)))
#define AS3 __attribute__((address_space(3)))

// ---------------------------------------------------------------------------
__global__ void k_detect(const int* __restrict__ ei, int* __restrict__ flag) {
    if (threadIdx.x == 0 && blockIdx.x == 0) {
        int f = 1;
        for (int i = 0; i < 32; ++i) {
            if (ei[2 * i + 1] != 0) { f = 0; break; }
        }
        *flag = f;
    }
}

__device__ __forceinline__ int load_row(const int* ei, int f, int e) {
    return f ? ei[2 * e] : ei[e];
}
__device__ __forceinline__ int load_col(const int* ei, int f, int e) {
    return f ? ei[2 * (EE + e)] : ei[EE + e];
}

// ---------------------------------------------------------------------------
// Fused: per-destination degree atomics (blocks 0..247) + weight prep
// (blocks 248..347).
__global__ void k_deg_prep(const int* __restrict__ ei, const int* __restrict__ flag,
                           const float* __restrict__ ew,
                           float* __restrict__ deg, int* __restrict__ cnt,
                           const float* __restrict__ Wc2, _Float16* __restrict__ w2p,
                           const float* __restrict__ Wc1, _Float16* __restrict__ w1p,
                           const float* __restrict__ Wg, _Float16* __restrict__ wgp) {
    int b = blockIdx.x;
    if (b < EE / 256) {
        int e = b * 256 + threadIdx.x;
        int f = *flag;
        int c = load_col(ei, f, e);
        atomicAdd(&deg[c], ew[e]);
        atomicAdd(&cnt[c], 1);
        return;
    }
    int i = (b - EE / 256) * 256 + threadIdx.x;
    if (i < 16384) {
        // conv2 B-frags: slot=(s*4+lg)*128+nt*16+c, elem e
        int e = i & 7;
        int slot = i >> 3;
        int c  = slot & 15;
        int nt = (slot >> 4) & 7;
        int g  = (slot >> 7) & 3;
        int s  = (slot >> 9) & 3;
        int ci = g * 4 + (e >> 1);
        w2p[i] = (_Float16)Wc2[(nt * 16 + c) * 128 + ci * 8 + 2 * s + (e & 1)];
    } else if (i < 16384 + 8192) {
        // conv1 GEMM1 A-frags with sigma channel permutation
        int j = i - 16384;
        int e = j & 7;
        int m = (j >> 3) & 127;
        int slg = j >> 10;              // 0..7 = s*4+lg
        int ci = (slg >> 2) * 4 + (slg & 3);
        int hi = m >> 6;                // 0 = P, 1 = Q
        int mb = m & 63;
        int mt = mb >> 4, r = mb & 15;
        int sig = hi * 64 + 32 * (mt >> 1) + 8 * (r >> 2) + 4 * (mt & 1) + (r & 3);
        w1p[j] = (ci < CIN) ? (_Float16)Wc1[sig * (CIN * KK) + ci * KK + e]
                            : (_Float16)0.0f;
    } else if (i < 16384 + 8192 + 1024) {
        // conv1 GEMM2 B-frags (Wg)
        int j = i - 16384 - 8192;
        int e = j & 7;
        int f = (j >> 3) & 15;
        int slg = j >> 7;               // 0..7
        int c = (slg >> 2) * 32 + (slg & 3) * 8 + e;
        wgp[j] = (_Float16)Wg[c * H2C + f];
    }
}

__global__ void k_scan(const int* __restrict__ cnt, int* __restrict__ offs,
                       int* __restrict__ cursor) {
    __shared__ int part[1024];
    int tid = threadIdx.x;
    int base = tid * 8;
    int local[8];
    int s = 0;
#pragma unroll
    for (int j = 0; j < 8; ++j) {
        int idx = base + j;
        int v = (idx < NN) ? cnt[idx] : 0;
        local[j] = s;
        s += v;
    }
    part[tid] = s;
    __syncthreads();
    for (int d = 1; d < 1024; d <<= 1) {
        int v = 0;
        if (tid >= d) v = part[tid - d];
        __syncthreads();
        if (tid >= d) part[tid] += v;
        __syncthreads();
    }
    int ex = (tid > 0) ? part[tid - 1] : 0;
#pragma unroll
    for (int j = 0; j < 8; ++j) {
        int idx = base + j;
        if (idx < NN) {
            offs[idx] = ex + local[j];
            cursor[idx] = ex + local[j];
        }
    }
    if (tid == 1023) offs[NN] = part[1023];
}

// ---------------------------------------------------------------------------
// Merged kernel: blocks [0, NN/4) run conv1 (register-resident, wave = node);
// blocks [NN/4, NN/4+EE/256) run the edge bucket-fill.
__global__ __launch_bounds__(256, 3) void k_conv1_fill(
        const float* __restrict__ x, const _Float16* __restrict__ w1p,
        const float* __restrict__ b1, const _Float16* __restrict__ wgp,
        _Float16* __restrict__ xt,
        const int* __restrict__ ei, const int* __restrict__ flag,
        const float* __restrict__ ew, const float* __restrict__ deg,
        int* __restrict__ cursor, int2* __restrict__ em) {
    if (blockIdx.x >= NN / 4) {
        // ---- bucket fill: em[pos] = (src, dinv[src]*ew) ----
        int e = (blockIdx.x - NN / 4) * 256 + threadIdx.x;
        if (e < EE) {
            int f = *flag;
            int c = load_col(ei, f, e);
            int r = load_row(ei, f, e);
            int pos = atomicAdd(&cursor[c], 1);
            em[pos] = make_int2(r, __float_as_int(rsqrtf(deg[r] + 1.0f) * ew[e]));
        }
        return;
    }
    // ---- conv1, fully register-resident (zero LDS, zero barriers) ----
    int tid = threadIdx.x;
    int w = tid >> 6, lane = tid & 63;
    int lc = lane & 15, lg = lane >> 4;
    int n = blockIdx.x * 4 + w;
    const float* xg = x + (size_t)n * (CIN * WW);

    const half8* w1v = (const half8*)w1p;
    const half8* wgv = (const half8*)wgp;

    half8 av[2][8];
#pragma unroll
    for (int s = 0; s < 2; ++s)
#pragma unroll
        for (int mt = 0; mt < 8; ++mt)
            av[s][mt] = w1v[(s * 4 + lg) * 128 + mt * 16 + lc];
    half8 bw[2];
#pragma unroll
    for (int s2 = 0; s2 < 2; ++s2) bw[s2] = wgv[(s2 * 4 + lg) * 16 + lc];

    const float* xr0 = xg + (size_t)lg * WW;
    const float* xr1 = xg + (size_t)(4 + lg) * WW;
    bool cok1 = (4 + lg) < CIN;

    f32x4 acc2[4];
#pragma unroll
    for (int mt2 = 0; mt2 < 4; ++mt2) acc2[mt2] = (f32x4)0.0f;

#pragma unroll
    for (int nt = 0; nt < 4; ++nt) {
        int t = nt * 16 + lc;
        half8 bf0, bf1;
#pragma unroll
        for (int e = 0; e < 8; ++e) {
            int tp = t + e;
            bf0[e] = (_Float16)((tp < WW) ? xr0[tp] : 0.0f);
            bf1[e] = (_Float16)((cok1 && tp < WW) ? xr1[tp] : 0.0f);
        }
        f32x4 acc[8];
#pragma unroll
        for (int mt = 0; mt < 8; ++mt) acc[mt] = (f32x4)0.0f;
#pragma unroll
        for (int mt = 0; mt < 8; ++mt)
            acc[mt] = __builtin_amdgcn_mfma_f32_16x16x32_f16(av[0][mt], bf0,
                                                             acc[mt], 0, 0, 0);
#pragma unroll
        for (int mt = 0; mt < 8; ++mt)
            acc[mt] = __builtin_amdgcn_mfma_f32_16x16x32_f16(av[1][mt], bf1,
                                                             acc[mt], 0, 0, 0);
        half4 h4[4];
#pragma unroll
        for (int mtp = 0; mtp < 4; ++mtp) {
            int cb = 32 * (mtp >> 1) + 8 * lg + 4 * (mtp & 1);
            float4 bP = *(const float4*)(b1 + cb);
            float4 bQ = *(const float4*)(b1 + 64 + cb);
            f32x4 P = acc[mtp];
            f32x4 Q = acc[mtp + 4];
            half4 hh;
            hh[0] = (_Float16)((P[0] + bP.x) * (1.0f / (1.0f + __expf(-(Q[0] + bQ.x)))));
            hh[1] = (_Float16)((P[1] + bP.y) * (1.0f / (1.0f + __expf(-(Q[1] + bQ.y)))));
            hh[2] = (_Float16)((P[2] + bP.z) * (1.0f / (1.0f + __expf(-(Q[2] + bQ.z)))));
            hh[3] = (_Float16)((P[3] + bP.w) * (1.0f / (1.0f + __expf(-(Q[3] + bQ.w)))));
            h4[mtp] = hh;
        }
#pragma unroll
        for (int s2 = 0; s2 < 2; ++s2) {
            half8 af = __builtin_shufflevector(h4[2 * s2], h4[2 * s2 + 1],
                                               0, 1, 2, 3, 4, 5, 6, 7);
            acc2[nt] = __builtin_amdgcn_mfma_f32_16x16x32_f16(af, bw[s2],
                                                              acc2[nt], 0, 0, 0);
        }
    }

    _Float16* xtn = xt + (size_t)n * FT;
#pragma unroll
    for (int mt2 = 0; mt2 < 4; ++mt2) {
#pragma unroll
        for (int j = 0; j < 4; ++j) {
            int t = mt2 * 16 + 4 * lg + j;
            if (t < T1) xtn[t * 16 + lc] = (_Float16)acc2[mt2][j];
        }
    }
}

// ---------------------------------------------------------------------------
// Fused gather + conv2. Wave = 1 node (r1 structure).
// Gather pipelining via LDS (zero VGPRs of row state — r3/r4's register rings
// both spilled to scratch): per-wave 4-slot LDS ring, each row prefetched by
// 2x global_load_lds dwordx4 (part A 1024B all lanes; part B exec-masked
// lanes<50). Counted `s_waitcnt vmcnt(6)` before consuming a slot keeps 3
// rows in flight (m201 pattern); row read-back via inline-asm ds_read_b128 x2
// fused with lgkmcnt(0) in ONE asm block (data-dep-safe; hides the LDS dep so
// the compiler can't insert a pessimistic vmcnt(0)). em entries kept 4-ahead
// in an int2 register ring so no address use forces a drain. Tail handled by
// zero-weight self-row padding (constant issue rate -> constant vmcnt).
// Epilogue unchanged: gs/gout live in the (drained) ring; LDS-staged
// coalesced NONTEMPORAL stores (keeps the write stream out of L2 so xt stays
// resident -> FETCH 102 vs 154MB, proven r1 vs r2).
__global__ __launch_bounds__(256, 4) void k_gc2(
        const _Float16* __restrict__ xt, const float* __restrict__ deg,
        const int* __restrict__ offs, const int2* __restrict__ em,
        const float* __restrict__ bg, const _Float16* __restrict__ w2p,
        const float* __restrict__ b2, float* __restrict__ out) {
    // 4 slots x 1856B + 256B pad (lane-63 part-B ds_read over-reads slot end)
    __shared__ __align__(16) char ring[4][7680];
    int tid = threadIdx.x;
    int w = tid >> 6, lane = tid & 63;
    int lc = lane & 15, lg = lane >> 4;
    int n = blockIdx.x * 4 + w;
    bool hi = lane < 50;                // part B covers row bytes [1024,1824)

    char* rb = ring[w];
    unsigned aBase = (unsigned)(unsigned long long)(void*)rb + (unsigned)lane * 16u;

    float dc = rsqrtf(deg[n] + 1.0f);
    float a0[8], a1[8];
    {
        const half8* xs = (const half8*)(xt + (size_t)n * FT);
        half8 u0 = xs[lane];
        half8 u1 = (half8)(_Float16)0.0f;
        if (hi) u1 = xs[64 + lane];
        float sw = dc * dc;
#pragma unroll
        for (int j = 0; j < 8; ++j) {
            a0[j] = (float)u0[j] * sw;
            a1[j] = (float)u1[j] * sw;
        }
    }
    int beg = __builtin_amdgcn_readfirstlane(offs[n]);
    int m   = __builtin_amdgcn_readfirstlane(offs[n + 1]) - beg;

    // pad entries read the self row with weight 0 (constant issue rate)
#define LDEM(K) (((K) < m) ? em[beg + (K)] : make_int2(n, 0))
#define PREF(SOFF, EV, WREG) {                                                \
        WREG = __int_as_float((EV).y) * dc;                                   \
        const char* rp = (const char*)(xt + (size_t)(EV).x * FT)              \
                         + (size_t)lane * 16;                                 \
        __builtin_amdgcn_global_load_lds((AS1 const void*)rp,                 \
                                         (AS3 void*)(rb + (SOFF)), 16, 0, 0); \
        if (hi)                                                               \
            __builtin_amdgcn_global_load_lds((AS1 const void*)(rp + 1024),    \
                                             (AS3 void*)(rb + (SOFF) + 1024), \
                                             16, 0, 0);                       \
    }
    // consume slot: vmcnt(6) -> oldest row's 2 loads done (in-order retire;
    // conservative even if em loads stay vector). ds_read+lgkmcnt fused.
#define GSTEP(OFFA, OFFB, SOFF, EREG, WREG, NIDX) {                           \
        asm volatile("s_waitcnt vmcnt(6)" ::: "memory");                      \
        i32x4 rA, rB;                                                         \
        asm volatile("ds_read_b128 %0, %2 offset:" OFFA "\n\t"                \
                     "ds_read_b128 %1, %2 offset:" OFFB "\n\t"                \
                     "s_waitcnt lgkmcnt(0)"                                   \
                     : "=&v"(rA), "=&v"(rB) : "v"(aBase) : "memory");         \
        half8 dA = __builtin_bit_cast(half8, rA);                             \
        half8 dB = __builtin_bit_cast(half8, rB);                             \
        float wv = WREG;                                                      \
        _Pragma("unroll")                                                     \
        for (int j = 0; j < 8; ++j) {                                         \
            a0[j] += (float)dA[j] * wv;                                       \
            a1[j] += (float)dB[j] * wv;                                       \
        }                                                                     \
        PREF(SOFF, EREG, WREG)                                                \
        EREG = LDEM(NIDX);                                                    \
    }

    float W0, W1, W2, W3;
    {
        // prologue em loads BEFORE the drain so their waits fold into it
        int2 e0 = LDEM(0), e1 = LDEM(1), e2 = LDEM(2), e3 = LDEM(3);
        // pin the vmcnt count: nothing outstanding when the ring starts
        asm volatile("s_waitcnt vmcnt(0)" ::: "memory");
        PREF(0,    e0, W0)
        PREF(1856, e1, W1)
        PREF(3712, e2, W2)
        PREF(5568, e3, W3)
    }
    int2 E0 = LDEM(4), E1 = LDEM(5), E2 = LDEM(6), E3 = LDEM(7);

    int mm = (m + 3) & ~3;
    for (int i = 0; i < mm; i += 4) {
        GSTEP("0",    "1024", 0,    E0, W0, i + 8)
        GSTEP("1856", "2880", 1856, E1, W1, i + 9)
        GSTEP("3712", "4736", 3712, E2, W2, i + 10)
        GSTEP("5568", "6592", 5568, E3, W3, i + 11)
    }
    // drain all in-flight prefetches before reusing the ring as gs/gout
    asm volatile("s_waitcnt vmcnt(0)" ::: "memory");
    __builtin_amdgcn_sched_barrier(0);
#undef GSTEP
#undef PREF
#undef LDEM

    // relu + bias -> gs[f][t] (f16, stride 58) in ring bytes [0,1856).
    {
        _Float16* g = (_Float16*)rb;
        int f0 = (lane & 1) * 8;
        int t0 = lane >> 1;
        float4 bgA = *(const float4*)(bg + f0);
        float4 bgB = *(const float4*)(bg + f0 + 4);
        float bv[8] = {bgA.x, bgA.y, bgA.z, bgA.w, bgB.x, bgB.y, bgB.z, bgB.w};
#pragma unroll
        for (int j = 0; j < 8; ++j) {
            g[(f0 + j) * 58 + t0] = (_Float16)fmaxf(a0[j] + bv[j], 0.0f);
            if (hi) g[(f0 + j) * 58 + 32 + t0] = (_Float16)fmaxf(a1[j] + bv[j], 0.0f);
        }
    }
    // wave-private LDS region: compiler orders write->read via lgkmcnt,
    // no __syncthreads needed (waves fully independent).

    const _Float16* g = (const _Float16*)rb;
    half8 af[4][4];
#pragma unroll
    for (int s = 0; s < 4; ++s)
#pragma unroll
        for (int mt = 0; mt < 4; ++mt) {
            int tb = mt * 16 + lc + 2 * s;
            half8 v;
#pragma unroll
            for (int j = 0; j < 4; ++j) {
                int ci = lg * 4 + j;
                v[2 * j]     = g[ci * 58 + tb];
                v[2 * j + 1] = g[ci * 58 + tb + 1];
            }
            af[s][mt] = v;
        }

    const half8* wsv = (const half8*)w2p;
    float* outn = out + (size_t)n * (H1C * T2);
    float* go = (float*)(rb + 1856);    // 3200B staging, disjoint from gs
#pragma unroll
    for (int ntp = 0; ntp < 4; ++ntp) {
        f32x4 aP[4], aQ[4];
#pragma unroll
        for (int mt = 0; mt < 4; ++mt) { aP[mt] = (f32x4)0.0f; aQ[mt] = (f32x4)0.0f; }
#pragma unroll
        for (int s = 0; s < 4; ++s) {
            half8 bP = wsv[(s * 4 + lg) * 128 + ntp * 16 + lc];
            half8 bQ = wsv[(s * 4 + lg) * 128 + (ntp + 4) * 16 + lc];
#pragma unroll
            for (int mt = 0; mt < 4; ++mt) {
                aP[mt] = __builtin_amdgcn_mfma_f32_16x16x32_f16(af[s][mt], bP,
                                                                aP[mt], 0, 0, 0);
                aQ[mt] = __builtin_amdgcn_mfma_f32_16x16x32_f16(af[s][mt], bQ,
                                                                aQ[mt], 0, 0, 0);
            }
        }
        int c = ntp * 16 + lc;
        float bp = b2[c], bq = b2[64 + c];
        // stage [lc][t<50] into wave-private LDS (column-major rows of 50)
#pragma unroll
        for (int mt = 0; mt < 4; ++mt) {
#pragma unroll
            for (int e2 = 0; e2 < 4; ++e2) {
                int t = mt * 16 + lg * 4 + e2;
                if (t < T2) {
                    float vv = (aP[mt][e2] + bp) *
                               (1.0f / (1.0f + __expf(-(aQ[mt][e2] + bq))));
                    go[lc * T2 + t] = vv;
                }
            }
        }
        // coalesced nontemporal writeback: 800 floats = 3x1024B + 128B
        float* dst = outn + ntp * (16 * T2);
#pragma unroll
        for (int i = 0; i < 3; ++i) {
            f32x4 v = *(const f32x4*)(go + i * 256 + lane * 4);
            __builtin_nontemporal_store(v, (f32x4*)(dst + i * 256 + lane * 4));
        }
        if (lane < 8) {
            f32x4 v = *(const f32x4*)(go + 768 + lane * 4);
            __builtin_nontemporal_store(v, (f32x4*)(dst + 768 + lane * 4));
        }
    }
}

// ---------------------------------------------------------------------------
extern "C" void kernel_launch(void* const* d_in, const int* in_sizes, int n_in,
                              void* d_out, int out_size, void* d_ws, size_t ws_size,
                              hipStream_t stream) {
    const float* x   = (const float*)d_in[0];
    const int*   ei  = (const int*)d_in[1];
    const float* ea  = (const float*)d_in[2];
    const float* Wc1 = (const float*)d_in[4];
    const float* b1  = (const float*)d_in[5];
    const float* Wg  = (const float*)d_in[6];
    const float* bg  = (const float*)d_in[7];
    const float* Wc2 = (const float*)d_in[8];
    const float* b2  = (const float*)d_in[9];
    float* out = (float*)d_out;

    char* ws = (char*)d_ws;
    size_t off = 0;
    auto alloc = [&](size_t bytes) -> void* {
        void* p = ws + off;
        off += (bytes + 255) & ~(size_t)255;
        return p;
    };
    int*      flag   = (int*)alloc(4);
    float*    deg    = (float*)alloc((size_t)NN * 4);
    int*      cnt    = (int*)alloc((size_t)NN * 4);
    int*      offs   = (int*)alloc((size_t)(NN + 1) * 4);
    int*      cursor = (int*)alloc((size_t)NN * 4);
    int2*     em     = (int2*)alloc((size_t)EE * 8);
    _Float16* xt     = (_Float16*)alloc((size_t)NN * FT * 2);
    _Float16* w2p    = (_Float16*)alloc((size_t)16384 * 2);
    _Float16* w1p    = (_Float16*)alloc((size_t)8192 * 2);
    _Float16* wgp    = (_Float16*)alloc((size_t)1024 * 2);
    (void)ws_size; (void)in_sizes; (void)n_in; (void)out_size;

    hipMemsetAsync(deg, 0, (size_t)NN * 4, stream);
    hipMemsetAsync(cnt, 0, (size_t)NN * 4, stream);
    k_detect<<<1, 64, 0, stream>>>(ei, flag);
    k_deg_prep<<<EE / 256 + 100, 256, 0, stream>>>(ei, flag, ea, deg, cnt,
                                                   Wc2, w2p, Wc1, w1p, Wg, wgp);
    k_scan<<<1, 1024, 0, stream>>>(cnt, offs, cursor);
    k_conv1_fill<<<NN / 4 + EE / 256, 256, 0, stream>>>(x, w1p, b1, wgp, xt,
                                                        ei, flag, ea, deg,
                                                        cursor, em);
    k_gc2<<<NN / 4, 256, 0, stream>>>(xt, deg, offs, em, bg, w2p, b2, out);
}

// Round 6
// 126.466 us; speedup vs baseline: 1.3520x; 1.3006x over previous
//
#include <hip/hip_runtime.h>
#include <hip/hip_bf16.h>

#define NN 7936
#define EE 63488
#define CIN 5
#define WW 64
#define KK 8
#define H1C 64
#define H2C 16
#define T1 57            // 64-8+1
#define T2 50            // 57-8+1
#define FT (T1*H2C)      // 912 elems per node for xt (f16)

typedef _Float16 half8 __attribute__((ext_vector_type(8)));
typedef _Float16 half4 __attribute__((ext_vector_type(4)));
typedef float f32x4 __attribute__((ext_vector_type(4)));

// ---------------------------------------------------------------------------
// Per-block int64-layout detection (replaces the serializing k_detect kernel):
// first wave checks high words of the first 32 edge indices, ballot, LDS
// broadcast. ~32 L2-hot ints per block — negligible.
__device__ __forceinline__ int block_flag(const int* __restrict__ ei,
                                          int* sflag) {
    if (threadIdx.x < 64) {
        int bad = (threadIdx.x < 32) ? (ei[2 * threadIdx.x + 1] != 0) : 0;
        unsigned long long b = __ballot(bad);
        if (threadIdx.x == 0) *sflag = (b == 0ULL) ? 1 : 0;
    }
    __syncthreads();
    return *sflag;
}

__device__ __forceinline__ int load_row(const int* ei, int f, int e) {
    return f ? ei[2 * e] : ei[e];
}
__device__ __forceinline__ int load_col(const int* ei, int f, int e) {
    return f ? ei[2 * (EE + e)] : ei[EE + e];
}

// ---------------------------------------------------------------------------
// Fused: per-destination degree atomics (blocks 0..247) + weight prep
// (blocks 248..347). Flag recomputed per edge-block (no k_detect dependency).
__global__ void k_deg_prep(const int* __restrict__ ei,
                           const float* __restrict__ ew,
                           float* __restrict__ deg, int* __restrict__ cnt,
                           const float* __restrict__ Wc2, _Float16* __restrict__ w2p,
                           const float* __restrict__ Wc1, _Float16* __restrict__ w1p,
                           const float* __restrict__ Wg, _Float16* __restrict__ wgp) {
    __shared__ int sflag;
    int b = blockIdx.x;
    if (b < EE / 256) {
        int f = block_flag(ei, &sflag);
        int e = b * 256 + threadIdx.x;
        int c = load_col(ei, f, e);
        atomicAdd(&deg[c], ew[e]);
        atomicAdd(&cnt[c], 1);
        return;
    }
    int i = (b - EE / 256) * 256 + threadIdx.x;
    if (i < 16384) {
        // conv2 B-frags: slot=(s*4+lg)*128+nt*16+c, elem e
        int e = i & 7;
        int slot = i >> 3;
        int c  = slot & 15;
        int nt = (slot >> 4) & 7;
        int g  = (slot >> 7) & 3;
        int s  = (slot >> 9) & 3;
        int ci = g * 4 + (e >> 1);
        w2p[i] = (_Float16)Wc2[(nt * 16 + c) * 128 + ci * 8 + 2 * s + (e & 1)];
    } else if (i < 16384 + 8192) {
        // conv1 GEMM1 A-frags with sigma channel permutation
        int j = i - 16384;
        int e = j & 7;
        int m = (j >> 3) & 127;
        int slg = j >> 10;              // 0..7 = s*4+lg
        int ci = (slg >> 2) * 4 + (slg & 3);
        int hi = m >> 6;                // 0 = P, 1 = Q
        int mb = m & 63;
        int mt = mb >> 4, r = mb & 15;
        int sig = hi * 64 + 32 * (mt >> 1) + 8 * (r >> 2) + 4 * (mt & 1) + (r & 3);
        w1p[j] = (ci < CIN) ? (_Float16)Wc1[sig * (CIN * KK) + ci * KK + e]
                            : (_Float16)0.0f;
    } else if (i < 16384 + 8192 + 1024) {
        // conv1 GEMM2 B-frags (Wg)
        int j = i - 16384 - 8192;
        int e = j & 7;
        int f = (j >> 3) & 15;
        int slg = j >> 7;               // 0..7
        int c = (slg >> 2) * 32 + (slg & 3) * 8 + e;
        wgp[j] = (_Float16)Wg[c * H2C + f];
    }
}

// ---------------------------------------------------------------------------
// Bucket-base reservation (replaces the 1-block serial prefix scan): bucket
// bases may be assigned in ARBITRARY order — the gather only needs each
// destination's edges contiguous. Wave shuffle-scan of cnt + ONE atomicAdd
// per wave (124 total) on a global cursor. 31 blocks, fully parallel.
__global__ void k_reserve(const int* __restrict__ cnt, int* __restrict__ gcur,
                          int* __restrict__ offs, int* __restrict__ cursor) {
    int n = blockIdx.x * 256 + threadIdx.x;
    int lane = threadIdx.x & 63;
    int c = (n < NN) ? cnt[n] : 0;
    int s = c;
#pragma unroll
    for (int d = 1; d < 64; d <<= 1) {
        int t = __shfl_up(s, d);
        if (lane >= d) s += t;
    }
    int total = __shfl(s, 63);
    int base = 0;
    if (lane == 63) base = atomicAdd(gcur, total);
    base = __shfl(base, 63);
    int beg = base + s - c;             // exclusive within wave
    if (n < NN) {
        offs[n] = beg;
        cursor[n] = beg;
    }
}

// ---------------------------------------------------------------------------
// Merged kernel: blocks [0, NN/4) run conv1 (register-resident, wave = node);
// blocks [NN/4, NN/4+EE/256) run the edge bucket-fill.
__global__ __launch_bounds__(256, 3) void k_conv1_fill(
        const float* __restrict__ x, const _Float16* __restrict__ w1p,
        const float* __restrict__ b1, const _Float16* __restrict__ wgp,
        _Float16* __restrict__ xt,
        const int* __restrict__ ei,
        const float* __restrict__ ew, const float* __restrict__ deg,
        int* __restrict__ cursor, int2* __restrict__ em) {
    if (blockIdx.x >= NN / 4) {
        // ---- bucket fill: em[pos] = (src, dinv[src]*ew) ----
        __shared__ int sflag;
        int f = block_flag(ei, &sflag);
        int e = (blockIdx.x - NN / 4) * 256 + threadIdx.x;
        if (e < EE) {
            int c = load_col(ei, f, e);
            int r = load_row(ei, f, e);
            int pos = atomicAdd(&cursor[c], 1);
            em[pos] = make_int2(r, __float_as_int(rsqrtf(deg[r] + 1.0f) * ew[e]));
        }
        return;
    }
    // ---- conv1, fully register-resident (zero LDS, zero barriers) ----
    int tid = threadIdx.x;
    int w = tid >> 6, lane = tid & 63;
    int lc = lane & 15, lg = lane >> 4;
    int n = blockIdx.x * 4 + w;
    const float* xg = x + (size_t)n * (CIN * WW);

    const half8* w1v = (const half8*)w1p;
    const half8* wgv = (const half8*)wgp;

    half8 av[2][8];
#pragma unroll
    for (int s = 0; s < 2; ++s)
#pragma unroll
        for (int mt = 0; mt < 8; ++mt)
            av[s][mt] = w1v[(s * 4 + lg) * 128 + mt * 16 + lc];
    half8 bw[2];
#pragma unroll
    for (int s2 = 0; s2 < 2; ++s2) bw[s2] = wgv[(s2 * 4 + lg) * 16 + lc];

    const float* xr0 = xg + (size_t)lg * WW;
    const float* xr1 = xg + (size_t)(4 + lg) * WW;
    bool cok1 = (4 + lg) < CIN;

    f32x4 acc2[4];
#pragma unroll
    for (int mt2 = 0; mt2 < 4; ++mt2) acc2[mt2] = (f32x4)0.0f;

#pragma unroll
    for (int nt = 0; nt < 4; ++nt) {
        int t = nt * 16 + lc;
        half8 bf0, bf1;
#pragma unroll
        for (int e = 0; e < 8; ++e) {
            int tp = t + e;
            bf0[e] = (_Float16)((tp < WW) ? xr0[tp] : 0.0f);
            bf1[e] = (_Float16)((cok1 && tp < WW) ? xr1[tp] : 0.0f);
        }
        f32x4 acc[8];
#pragma unroll
        for (int mt = 0; mt < 8; ++mt) acc[mt] = (f32x4)0.0f;
#pragma unroll
        for (int mt = 0; mt < 8; ++mt)
            acc[mt] = __builtin_amdgcn_mfma_f32_16x16x32_f16(av[0][mt], bf0,
                                                             acc[mt], 0, 0, 0);
#pragma unroll
        for (int mt = 0; mt < 8; ++mt)
            acc[mt] = __builtin_amdgcn_mfma_f32_16x16x32_f16(av[1][mt], bf1,
                                                             acc[mt], 0, 0, 0);
        half4 h4[4];
#pragma unroll
        for (int mtp = 0; mtp < 4; ++mtp) {
            int cb = 32 * (mtp >> 1) + 8 * lg + 4 * (mtp & 1);
            float4 bP = *(const float4*)(b1 + cb);
            float4 bQ = *(const float4*)(b1 + 64 + cb);
            f32x4 P = acc[mtp];
            f32x4 Q = acc[mtp + 4];
            half4 hh;
            hh[0] = (_Float16)((P[0] + bP.x) * (1.0f / (1.0f + __expf(-(Q[0] + bQ.x)))));
            hh[1] = (_Float16)((P[1] + bP.y) * (1.0f / (1.0f + __expf(-(Q[1] + bQ.y)))));
            hh[2] = (_Float16)((P[2] + bP.z) * (1.0f / (1.0f + __expf(-(Q[2] + bQ.z)))));
            hh[3] = (_Float16)((P[3] + bP.w) * (1.0f / (1.0f + __expf(-(Q[3] + bQ.w)))));
            h4[mtp] = hh;
        }
#pragma unroll
        for (int s2 = 0; s2 < 2; ++s2) {
            half8 af = __builtin_shufflevector(h4[2 * s2], h4[2 * s2 + 1],
                                               0, 1, 2, 3, 4, 5, 6, 7);
            acc2[nt] = __builtin_amdgcn_mfma_f32_16x16x32_f16(af, bw[s2],
                                                              acc2[nt], 0, 0, 0);
        }
    }

    _Float16* xtn = xt + (size_t)n * FT;
#pragma unroll
    for (int mt2 = 0; mt2 < 4; ++mt2) {
#pragma unroll
        for (int j = 0; j < 4; ++j) {
            int t = mt2 * 16 + 4 * lg + j;
            if (t < T1) xtn[t * 16 + lc] = (_Float16)acc2[mt2][j];
        }
    }
}

// ---------------------------------------------------------------------------
// Fused gather + conv2 — EXACT round-1 structure (measured best: 91 µs,
// FETCH 102MB, WRITE 183MB). Wave = 1 node, fully independent (no barriers).
// Gather: f16 xt loads (2x half8/lane), f32 accum, 2-deep software pipeline.
// Four deeper-pipeline schemes (reg ring x2, 2-wave split, LDS-DMA ring) all
// regressed: reg rings spill to scratch; global_load_lds loses L3 residency.
// gs: per-wave f16 [f][t] stride 58. conv2 B-frags straight from global w2p.
// Epilogue: stage each ntp-chunk in wave-private LDS, write back as coalesced
// NONTEMPORAL float4 streams (keeps the write stream out of L2 so xt stays
// L2/L3-resident; cached variants measured FETCH +52MB).
// Only change vs r1: m comes from cnt[n] (arbitrary-order bucket bases).
__global__ __launch_bounds__(256, 4) void k_gc2(
        const _Float16* __restrict__ xt, const float* __restrict__ deg,
        const int* __restrict__ offs, const int* __restrict__ cnt,
        const int2* __restrict__ em,
        const float* __restrict__ bg, const _Float16* __restrict__ w2p,
        const float* __restrict__ b2, float* __restrict__ out) {
    __shared__ _Float16 gs[4][952];              // [16][58] + pad, 7616 B
    __shared__ __align__(16) float gout[4][16 * T2];  // 3200 B per wave
    int tid = threadIdx.x;
    int w = tid >> 6, lane = tid & 63;
    int lc = lane & 15, lg = lane >> 4;
    int n = blockIdx.x * 4 + w;
    bool hi = lane < 50;                // second half8 covers elems 512..911

    float dc = rsqrtf(deg[n] + 1.0f);
    float a0[8], a1[8];
    {
        const half8* xs = (const half8*)(xt + (size_t)n * FT);
        half8 u0 = xs[lane];
        half8 u1 = (half8)(_Float16)0.0f;
        if (hi) u1 = xs[64 + lane];
        float sw = dc * dc;
#pragma unroll
        for (int j = 0; j < 8; ++j) {
            a0[j] = (float)u0[j] * sw;
            a1[j] = (float)u1[j] * sw;
        }
    }
    int beg = offs[n];
    int m = cnt[n];
    int2 rw0 = make_int2(0, 0), rw1 = make_int2(0, 0);
    half8 c0 = (half8)(_Float16)0.0f, c1 = (half8)(_Float16)0.0f;
    if (m > 0) {
        rw0 = em[beg];
        const half8* xr = (const half8*)(xt + (size_t)rw0.x * FT);
        c0 = xr[lane];
        if (hi) c1 = xr[64 + lane];
    }
    if (m > 1) rw1 = em[beg + 1];
    for (int i = 0; i < m; ++i) {
        float wv = __int_as_float(rw0.y) * dc;
        half8 d0 = c0, d1 = c1;
        int2 rwn = (i + 2 < m) ? em[beg + i + 2] : rw1;
        if (i + 1 < m) {
            const half8* xr = (const half8*)(xt + (size_t)rw1.x * FT);
            c0 = xr[lane];
            c1 = (half8)(_Float16)0.0f;
            if (hi) c1 = xr[64 + lane];
        }
        rw0 = rw1; rw1 = rwn;
#pragma unroll
        for (int j = 0; j < 8; ++j) {
            a0[j] += (float)d0[j] * wv;
            a1[j] += (float)d1[j] * wv;
        }
    }

    // relu + bias -> gs[f][t] (f16, stride 58). Lane owns f=(lane&1)*8+j,
    // t = lane>>1 (a0) and 32+(lane>>1) (a1, lanes<50).
    {
        _Float16* g = gs[w];
        int f0 = (lane & 1) * 8;
        int t0 = lane >> 1;
        float4 bgA = *(const float4*)(bg + f0);
        float4 bgB = *(const float4*)(bg + f0 + 4);
        float bv[8] = {bgA.x, bgA.y, bgA.z, bgA.w, bgB.x, bgB.y, bgB.z, bgB.w};
#pragma unroll
        for (int j = 0; j < 8; ++j) {
            g[(f0 + j) * 58 + t0] = (_Float16)fmaxf(a0[j] + bv[j], 0.0f);
            if (hi) g[(f0 + j) * 58 + 32 + t0] = (_Float16)fmaxf(a1[j] + bv[j], 0.0f);
        }
    }
    // wave-private LDS region: compiler orders write->read via lgkmcnt,
    // no __syncthreads needed (waves fully independent).

    const _Float16* g = gs[w];
    half8 af[4][4];
#pragma unroll
    for (int s = 0; s < 4; ++s)
#pragma unroll
        for (int mt = 0; mt < 4; ++mt) {
            int tb = mt * 16 + lc + 2 * s;
            half8 v;
#pragma unroll
            for (int j = 0; j < 4; ++j) {
                int ci = lg * 4 + j;
                v[2 * j]     = g[ci * 58 + tb];
                v[2 * j + 1] = g[ci * 58 + tb + 1];
            }
            af[s][mt] = v;
        }

    const half8* wsv = (const half8*)w2p;
    float* outn = out + (size_t)n * (H1C * T2);
    float* go = gout[w];
#pragma unroll
    for (int ntp = 0; ntp < 4; ++ntp) {
        f32x4 aP[4], aQ[4];
#pragma unroll
        for (int mt = 0; mt < 4; ++mt) { aP[mt] = (f32x4)0.0f; aQ[mt] = (f32x4)0.0f; }
#pragma unroll
        for (int s = 0; s < 4; ++s) {
            half8 bP = wsv[(s * 4 + lg) * 128 + ntp * 16 + lc];
            half8 bQ = wsv[(s * 4 + lg) * 128 + (ntp + 4) * 16 + lc];
#pragma unroll
            for (int mt = 0; mt < 4; ++mt) {
                aP[mt] = __builtin_amdgcn_mfma_f32_16x16x32_f16(af[s][mt], bP,
                                                                aP[mt], 0, 0, 0);
                aQ[mt] = __builtin_amdgcn_mfma_f32_16x16x32_f16(af[s][mt], bQ,
                                                                aQ[mt], 0, 0, 0);
            }
        }
        int c = ntp * 16 + lc;
        float bp = b2[c], bq = b2[64 + c];
        // stage [lc][t<50] into wave-private LDS (column-major rows of 50)
#pragma unroll
        for (int mt = 0; mt < 4; ++mt) {
#pragma unroll
            for (int e2 = 0; e2 < 4; ++e2) {
                int t = mt * 16 + lg * 4 + e2;
                if (t < T2) {
                    float vv = (aP[mt][e2] + bp) *
                               (1.0f / (1.0f + __expf(-(aQ[mt][e2] + bq))));
                    go[lc * T2 + t] = vv;
                }
            }
        }
        // coalesced nontemporal writeback: 800 floats = 3x1024B + 128B
        float* dst = outn + ntp * (16 * T2);
#pragma unroll
        for (int i = 0; i < 3; ++i) {
            f32x4 v = *(const f32x4*)(go + i * 256 + lane * 4);
            __builtin_nontemporal_store(v, (f32x4*)(dst + i * 256 + lane * 4));
        }
        if (lane < 8) {
            f32x4 v = *(const f32x4*)(go + 768 + lane * 4);
            __builtin_nontemporal_store(v, (f32x4*)(dst + 768 + lane * 4));
        }
    }
}

// ---------------------------------------------------------------------------
extern "C" void kernel_launch(void* const* d_in, const int* in_sizes, int n_in,
                              void* d_out, int out_size, void* d_ws, size_t ws_size,
                              hipStream_t stream) {
    const float* x   = (const float*)d_in[0];
    const int*   ei  = (const int*)d_in[1];
    const float* ea  = (const float*)d_in[2];
    const float* Wc1 = (const float*)d_in[4];
    const float* b1  = (const float*)d_in[5];
    const float* Wg  = (const float*)d_in[6];
    const float* bg  = (const float*)d_in[7];
    const float* Wc2 = (const float*)d_in[8];
    const float* b2  = (const float*)d_in[9];
    float* out = (float*)d_out;

    char* ws = (char*)d_ws;
    size_t off = 0;
    auto alloc = [&](size_t bytes) -> void* {
        void* p = ws + off;
        off += (bytes + 255) & ~(size_t)255;
        return p;
    };
    // deg | cnt | gcur contiguous -> single memset covers all three
    float*    deg    = (float*)alloc((size_t)NN * 4);   // 31744 (124*256)
    int*      cnt    = (int*)alloc((size_t)NN * 4);     // 31744
    int*      gcur   = (int*)alloc(4);                  // 256
    int*      offs   = (int*)alloc((size_t)NN * 4);
    int*      cursor = (int*)alloc((size_t)NN * 4);
    int2*     em     = (int2*)alloc((size_t)EE * 8);
    _Float16* xt     = (_Float16*)alloc((size_t)NN * FT * 2);
    _Float16* w2p    = (_Float16*)alloc((size_t)16384 * 2);
    _Float16* w1p    = (_Float16*)alloc((size_t)8192 * 2);
    _Float16* wgp    = (_Float16*)alloc((size_t)1024 * 2);
    (void)ws_size; (void)in_sizes; (void)n_in; (void)out_size;

    hipMemsetAsync(deg, 0, (size_t)NN * 4 * 2 + 256, stream);
    k_deg_prep<<<EE / 256 + 100, 256, 0, stream>>>(ei, ea, deg, cnt,
                                                   Wc2, w2p, Wc1, w1p, Wg, wgp);
    k_reserve<<<(NN + 255) / 256, 256, 0, stream>>>(cnt, gcur, offs, cursor);
    k_conv1_fill<<<NN / 4 + EE / 256, 256, 0, stream>>>(x, w1p, b1, wgp, xt,
                                                        ei, ea, deg,
                                                        cursor, em);
    k_gc2<<<NN / 4, 256, 0, stream>>>(xt, deg, offs, cnt, em, bg, w2p, b2, out);
}

// Round 7
// 117.218 us; speedup vs baseline: 1.4587x; 1.0789x over previous
//
#include <hip/hip_runtime.h>
#include <hip/hip_bf16.h>

#define NN 7936
#define EE 63488
#define CIN 5
#define WW 64
#define KK 8
#define H1C 64
#define H2C 16
#define T1 57            // 64-8+1
#define T2 50            // 57-8+1
#define FT (T1*H2C)      // 912 elems per node for xt (f16)
#define CAP 64           // fixed bucket capacity (P(deg>=64) ~ 1e-35)

typedef _Float16 half8 __attribute__((ext_vector_type(8)));
typedef _Float16 half4 __attribute__((ext_vector_type(4)));
typedef float f32x4 __attribute__((ext_vector_type(4)));

// ---------------------------------------------------------------------------
// Per-block int64-layout detection: first wave checks high words of the first
// 32 edge indices, ballot, LDS broadcast. ~32 L2-hot ints per block.
__device__ __forceinline__ int block_flag(const int* __restrict__ ei,
                                          int* sflag) {
    if (threadIdx.x < 64) {
        int bad = (threadIdx.x < 32) ? (ei[2 * threadIdx.x + 1] != 0) : 0;
        unsigned long long b = __ballot(bad);
        if (threadIdx.x == 0) *sflag = (b == 0ULL) ? 1 : 0;
    }
    __syncthreads();
    return *sflag;
}

__device__ __forceinline__ int load_row(const int* ei, int f, int e) {
    return f ? ei[2 * e] : ei[e];
}
__device__ __forceinline__ int load_col(const int* ei, int f, int e) {
    return f ? ei[2 * (EE + e)] : ei[EE + e];
}

// ---------------------------------------------------------------------------
// k_init: blocks 0..61 zero deg|cnt (contiguous 2*NN words, 62*256 = 15872
// exactly); blocks 62..161 do weight prep (25600 threads). Replaces the
// hipMemsetAsync + the weight half of the old k_deg_prep.
__global__ void k_init(float* __restrict__ deg,
                       const float* __restrict__ Wc2, _Float16* __restrict__ w2p,
                       const float* __restrict__ Wc1, _Float16* __restrict__ w1p,
                       const float* __restrict__ Wg, _Float16* __restrict__ wgp) {
    int b = blockIdx.x;
    if (b < 62) {
        // deg and cnt are contiguous in ws: zero both as one word range
        ((int*)deg)[b * 256 + threadIdx.x] = 0;
        return;
    }
    int i = (b - 62) * 256 + threadIdx.x;
    if (i < 16384) {
        // conv2 B-frags: slot=(s*4+lg)*128+nt*16+c, elem e
        int e = i & 7;
        int slot = i >> 3;
        int c  = slot & 15;
        int nt = (slot >> 4) & 7;
        int g  = (slot >> 7) & 3;
        int s  = (slot >> 9) & 3;
        int ci = g * 4 + (e >> 1);
        w2p[i] = (_Float16)Wc2[(nt * 16 + c) * 128 + ci * 8 + 2 * s + (e & 1)];
    } else if (i < 16384 + 8192) {
        // conv1 GEMM1 A-frags with sigma channel permutation
        int j = i - 16384;
        int e = j & 7;
        int m = (j >> 3) & 127;
        int slg = j >> 10;              // 0..7 = s*4+lg
        int ci = (slg >> 2) * 4 + (slg & 3);
        int hi = m >> 6;                // 0 = P, 1 = Q
        int mb = m & 63;
        int mt = mb >> 4, r = mb & 15;
        int sig = hi * 64 + 32 * (mt >> 1) + 8 * (r >> 2) + 4 * (mt & 1) + (r & 3);
        w1p[j] = (ci < CIN) ? (_Float16)Wc1[sig * (CIN * KK) + ci * KK + e]
                            : (_Float16)0.0f;
    } else if (i < 16384 + 8192 + 1024) {
        // conv1 GEMM2 B-frags (Wg)
        int j = i - 16384 - 8192;
        int e = j & 7;
        int f = (j >> 3) & 15;
        int slg = j >> 7;               // 0..7
        int c = (slg >> 2) * 32 + (slg & 3) * 8 + e;
        wgp[j] = (_Float16)Wg[c * H2C + f];
    }
}

// ---------------------------------------------------------------------------
// k_deg: single edge pass, ONE atomic per edge (the cnt atomic moved to the
// fill pass, which uses it as the bucket cursor).
__global__ void k_deg(const int* __restrict__ ei, const float* __restrict__ ew,
                      float* __restrict__ deg) {
    __shared__ int sflag;
    int f = block_flag(ei, &sflag);
    int e = blockIdx.x * 256 + threadIdx.x;
    int c = load_col(ei, f, e);
    atomicAdd(&deg[c], ew[e]);
}

// ---------------------------------------------------------------------------
// Merged kernel: blocks [0, NN/4) run conv1 (register-resident, wave = node);
// blocks [NN/4, NN/4+EE/256) run the edge bucket-fill into FIXED-CAPACITY
// buckets em[c*64+pos] (pos = atomicAdd cursor; no prefix scan needed — the
// gather only requires each destination's edges contiguous).
__global__ __launch_bounds__(256, 3) void k_conv1_fill(
        const float* __restrict__ x, const _Float16* __restrict__ w1p,
        const float* __restrict__ b1, const _Float16* __restrict__ wgp,
        _Float16* __restrict__ xt,
        const int* __restrict__ ei,
        const float* __restrict__ ew, const float* __restrict__ deg,
        int* __restrict__ cnt, int2* __restrict__ em) {
    if (blockIdx.x >= NN / 4) {
        // ---- bucket fill: em[c*64+pos] = (src, dinv[src]*ew) ----
        __shared__ int sflag;
        int f = block_flag(ei, &sflag);
        int e = (blockIdx.x - NN / 4) * 256 + threadIdx.x;
        if (e < EE) {
            int c = load_col(ei, f, e);
            int r = load_row(ei, f, e);
            int pos = atomicAdd(&cnt[c], 1);
            if (pos < CAP)
                em[(c << 6) + pos] =
                    make_int2(r, __float_as_int(rsqrtf(deg[r] + 1.0f) * ew[e]));
        }
        return;
    }
    // ---- conv1, fully register-resident (zero LDS, zero barriers) ----
    int tid = threadIdx.x;
    int w = tid >> 6, lane = tid & 63;
    int lc = lane & 15, lg = lane >> 4;
    int n = blockIdx.x * 4 + w;
    const float* xg = x + (size_t)n * (CIN * WW);

    const half8* w1v = (const half8*)w1p;
    const half8* wgv = (const half8*)wgp;

    half8 av[2][8];
#pragma unroll
    for (int s = 0; s < 2; ++s)
#pragma unroll
        for (int mt = 0; mt < 8; ++mt)
            av[s][mt] = w1v[(s * 4 + lg) * 128 + mt * 16 + lc];
    half8 bw[2];
#pragma unroll
    for (int s2 = 0; s2 < 2; ++s2) bw[s2] = wgv[(s2 * 4 + lg) * 16 + lc];

    const float* xr0 = xg + (size_t)lg * WW;
    const float* xr1 = xg + (size_t)(4 + lg) * WW;
    bool cok1 = (4 + lg) < CIN;

    f32x4 acc2[4];
#pragma unroll
    for (int mt2 = 0; mt2 < 4; ++mt2) acc2[mt2] = (f32x4)0.0f;

#pragma unroll
    for (int nt = 0; nt < 4; ++nt) {
        int t = nt * 16 + lc;
        half8 bf0, bf1;
#pragma unroll
        for (int e = 0; e < 8; ++e) {
            int tp = t + e;
            bf0[e] = (_Float16)((tp < WW) ? xr0[tp] : 0.0f);
            bf1[e] = (_Float16)((cok1 && tp < WW) ? xr1[tp] : 0.0f);
        }
        f32x4 acc[8];
#pragma unroll
        for (int mt = 0; mt < 8; ++mt) acc[mt] = (f32x4)0.0f;
#pragma unroll
        for (int mt = 0; mt < 8; ++mt)
            acc[mt] = __builtin_amdgcn_mfma_f32_16x16x32_f16(av[0][mt], bf0,
                                                             acc[mt], 0, 0, 0);
#pragma unroll
        for (int mt = 0; mt < 8; ++mt)
            acc[mt] = __builtin_amdgcn_mfma_f32_16x16x32_f16(av[1][mt], bf1,
                                                             acc[mt], 0, 0, 0);
        half4 h4[4];
#pragma unroll
        for (int mtp = 0; mtp < 4; ++mtp) {
            int cb = 32 * (mtp >> 1) + 8 * lg + 4 * (mtp & 1);
            float4 bP = *(const float4*)(b1 + cb);
            float4 bQ = *(const float4*)(b1 + 64 + cb);
            f32x4 P = acc[mtp];
            f32x4 Q = acc[mtp + 4];
            half4 hh;
            hh[0] = (_Float16)((P[0] + bP.x) * (1.0f / (1.0f + __expf(-(Q[0] + bQ.x)))));
            hh[1] = (_Float16)((P[1] + bP.y) * (1.0f / (1.0f + __expf(-(Q[1] + bQ.y)))));
            hh[2] = (_Float16)((P[2] + bP.z) * (1.0f / (1.0f + __expf(-(Q[2] + bQ.z)))));
            hh[3] = (_Float16)((P[3] + bP.w) * (1.0f / (1.0f + __expf(-(Q[3] + bQ.w)))));
            h4[mtp] = hh;
        }
#pragma unroll
        for (int s2 = 0; s2 < 2; ++s2) {
            half8 af = __builtin_shufflevector(h4[2 * s2], h4[2 * s2 + 1],
                                               0, 1, 2, 3, 4, 5, 6, 7);
            acc2[nt] = __builtin_amdgcn_mfma_f32_16x16x32_f16(af, bw[s2],
                                                              acc2[nt], 0, 0, 0);
        }
    }

    _Float16* xtn = xt + (size_t)n * FT;
#pragma unroll
    for (int mt2 = 0; mt2 < 4; ++mt2) {
#pragma unroll
        for (int j = 0; j < 4; ++j) {
            int t = mt2 * 16 + 4 * lg + j;
            if (t < T1) xtn[t * 16 + lc] = (_Float16)acc2[mt2][j];
        }
    }
}

// ---------------------------------------------------------------------------
// Fused gather + conv2 — EXACT round-1 structure (measured best: 91 µs,
// FETCH 102MB, WRITE 183MB). Wave = 1 node, fully independent (no barriers).
// Gather: f16 xt loads (2x half8/lane), f32 accum, 2-deep software pipeline.
// Only change vs r1: beg = n<<6 (fixed-cap bucket, kills the dependent
// offs[n] load) and m = min(cnt[n], CAP).
// Three deeper-pipeline schemes (reg ring x2, LDS-DMA ring) all regressed:
// reg rings spill to scratch at this VGPR budget; global_load_lds loses L3
// residency. Epilogue: LDS-staged coalesced NONTEMPORAL stores (keeps the
// write stream out of L2 so xt stays resident; cached variants FETCH +52MB).
__global__ __launch_bounds__(256, 4) void k_gc2(
        const _Float16* __restrict__ xt, const float* __restrict__ deg,
        const int* __restrict__ cnt, const int2* __restrict__ em,
        const float* __restrict__ bg, const _Float16* __restrict__ w2p,
        const float* __restrict__ b2, float* __restrict__ out) {
    __shared__ _Float16 gs[4][952];              // [16][58] + pad, 7616 B
    __shared__ __align__(16) float gout[4][16 * T2];  // 3200 B per wave
    int tid = threadIdx.x;
    int w = tid >> 6, lane = tid & 63;
    int lc = lane & 15, lg = lane >> 4;
    int n = blockIdx.x * 4 + w;
    bool hi = lane < 50;                // second half8 covers elems 512..911

    float dc = rsqrtf(deg[n] + 1.0f);
    float a0[8], a1[8];
    {
        const half8* xs = (const half8*)(xt + (size_t)n * FT);
        half8 u0 = xs[lane];
        half8 u1 = (half8)(_Float16)0.0f;
        if (hi) u1 = xs[64 + lane];
        float sw = dc * dc;
#pragma unroll
        for (int j = 0; j < 8; ++j) {
            a0[j] = (float)u0[j] * sw;
            a1[j] = (float)u1[j] * sw;
        }
    }
    int beg = n << 6;
    int m = min(cnt[n], CAP);
    int2 rw0 = make_int2(0, 0), rw1 = make_int2(0, 0);
    half8 c0 = (half8)(_Float16)0.0f, c1 = (half8)(_Float16)0.0f;
    if (m > 0) {
        rw0 = em[beg];
        const half8* xr = (const half8*)(xt + (size_t)rw0.x * FT);
        c0 = xr[lane];
        if (hi) c1 = xr[64 + lane];
    }
    if (m > 1) rw1 = em[beg + 1];
    for (int i = 0; i < m; ++i) {
        float wv = __int_as_float(rw0.y) * dc;
        half8 d0 = c0, d1 = c1;
        int2 rwn = (i + 2 < m) ? em[beg + i + 2] : rw1;
        if (i + 1 < m) {
            const half8* xr = (const half8*)(xt + (size_t)rw1.x * FT);
            c0 = xr[lane];
            c1 = (half8)(_Float16)0.0f;
            if (hi) c1 = xr[64 + lane];
        }
        rw0 = rw1; rw1 = rwn;
#pragma unroll
        for (int j = 0; j < 8; ++j) {
            a0[j] += (float)d0[j] * wv;
            a1[j] += (float)d1[j] * wv;
        }
    }

    // relu + bias -> gs[f][t] (f16, stride 58). Lane owns f=(lane&1)*8+j,
    // t = lane>>1 (a0) and 32+(lane>>1) (a1, lanes<50).
    {
        _Float16* g = gs[w];
        int f0 = (lane & 1) * 8;
        int t0 = lane >> 1;
        float4 bgA = *(const float4*)(bg + f0);
        float4 bgB = *(const float4*)(bg + f0 + 4);
        float bv[8] = {bgA.x, bgA.y, bgA.z, bgA.w, bgB.x, bgB.y, bgB.z, bgB.w};
#pragma unroll
        for (int j = 0; j < 8; ++j) {
            g[(f0 + j) * 58 + t0] = (_Float16)fmaxf(a0[j] + bv[j], 0.0f);
            if (hi) g[(f0 + j) * 58 + 32 + t0] = (_Float16)fmaxf(a1[j] + bv[j], 0.0f);
        }
    }
    // wave-private LDS region: compiler orders write->read via lgkmcnt,
    // no __syncthreads needed (waves fully independent).

    const _Float16* g = gs[w];
    half8 af[4][4];
#pragma unroll
    for (int s = 0; s < 4; ++s)
#pragma unroll
        for (int mt = 0; mt < 4; ++mt) {
            int tb = mt * 16 + lc + 2 * s;
            half8 v;
#pragma unroll
            for (int j = 0; j < 4; ++j) {
                int ci = lg * 4 + j;
                v[2 * j]     = g[ci * 58 + tb];
                v[2 * j + 1] = g[ci * 58 + tb + 1];
            }
            af[s][mt] = v;
        }

    const half8* wsv = (const half8*)w2p;
    float* outn = out + (size_t)n * (H1C * T2);
    float* go = gout[w];
#pragma unroll
    for (int ntp = 0; ntp < 4; ++ntp) {
        f32x4 aP[4], aQ[4];
#pragma unroll
        for (int mt = 0; mt < 4; ++mt) { aP[mt] = (f32x4)0.0f; aQ[mt] = (f32x4)0.0f; }
#pragma unroll
        for (int s = 0; s < 4; ++s) {
            half8 bP = wsv[(s * 4 + lg) * 128 + ntp * 16 + lc];
            half8 bQ = wsv[(s * 4 + lg) * 128 + (ntp + 4) * 16 + lc];
#pragma unroll
            for (int mt = 0; mt < 4; ++mt) {
                aP[mt] = __builtin_amdgcn_mfma_f32_16x16x32_f16(af[s][mt], bP,
                                                                aP[mt], 0, 0, 0);
                aQ[mt] = __builtin_amdgcn_mfma_f32_16x16x32_f16(af[s][mt], bQ,
                                                                aQ[mt], 0, 0, 0);
            }
        }
        int c = ntp * 16 + lc;
        float bp = b2[c], bq = b2[64 + c];
        // stage [lc][t<50] into wave-private LDS (column-major rows of 50)
#pragma unroll
        for (int mt = 0; mt < 4; ++mt) {
#pragma unroll
            for (int e2 = 0; e2 < 4; ++e2) {
                int t = mt * 16 + lg * 4 + e2;
                if (t < T2) {
                    float vv = (aP[mt][e2] + bp) *
                               (1.0f / (1.0f + __expf(-(aQ[mt][e2] + bq))));
                    go[lc * T2 + t] = vv;
                }
            }
        }
        // coalesced nontemporal writeback: 800 floats = 3x1024B + 128B
        float* dst = outn + ntp * (16 * T2);
#pragma unroll
        for (int i = 0; i < 3; ++i) {
            f32x4 v = *(const f32x4*)(go + i * 256 + lane * 4);
            __builtin_nontemporal_store(v, (f32x4*)(dst + i * 256 + lane * 4));
        }
        if (lane < 8) {
            f32x4 v = *(const f32x4*)(go + 768 + lane * 4);
            __builtin_nontemporal_store(v, (f32x4*)(dst + 768 + lane * 4));
        }
    }
}

// ---------------------------------------------------------------------------
extern "C" void kernel_launch(void* const* d_in, const int* in_sizes, int n_in,
                              void* d_out, int out_size, void* d_ws, size_t ws_size,
                              hipStream_t stream) {
    const float* x   = (const float*)d_in[0];
    const int*   ei  = (const int*)d_in[1];
    const float* ea  = (const float*)d_in[2];
    const float* Wc1 = (const float*)d_in[4];
    const float* b1  = (const float*)d_in[5];
    const float* Wg  = (const float*)d_in[6];
    const float* bg  = (const float*)d_in[7];
    const float* Wc2 = (const float*)d_in[8];
    const float* b2  = (const float*)d_in[9];
    float* out = (float*)d_out;

    char* ws = (char*)d_ws;
    size_t off = 0;
    auto alloc = [&](size_t bytes) -> void* {
        void* p = ws + off;
        off += (bytes + 255) & ~(size_t)255;
        return p;
    };
    // deg | cnt contiguous -> k_init zeroes both as one 2*NN word range
    float*    deg = (float*)alloc((size_t)NN * 4);      // 31744
    int*      cnt = (int*)alloc((size_t)NN * 4);        // 31744
    int2*     em  = (int2*)alloc((size_t)NN * CAP * 8); // 4.06 MB fixed-cap
    _Float16* xt  = (_Float16*)alloc((size_t)NN * FT * 2);
    _Float16* w2p = (_Float16*)alloc((size_t)16384 * 2);
    _Float16* w1p = (_Float16*)alloc((size_t)8192 * 2);
    _Float16* wgp = (_Float16*)alloc((size_t)1024 * 2);
    (void)ws_size; (void)in_sizes; (void)n_in; (void)out_size;

    k_init<<<162, 256, 0, stream>>>(deg, Wc2, w2p, Wc1, w1p, Wg, wgp);
    k_deg<<<EE / 256, 256, 0, stream>>>(ei, ea, deg);
    k_conv1_fill<<<NN / 4 + EE / 256, 256, 0, stream>>>(x, w1p, b1, wgp, xt,
                                                        ei, ea, deg, cnt, em);
    k_gc2<<<NN / 4, 256, 0, stream>>>(xt, deg, cnt, em, bg, w2p, b2, out);
}

// Round 8
// 103.794 us; speedup vs baseline: 1.6473x; 1.1293x over previous
//
#include <hip/hip_runtime.h>
#include <hip/hip_bf16.h>

#define NN 7936
#define EE 63488
#define CIN 5
#define WW 64
#define KK 8
#define H1C 64
#define H2C 16
#define T1 57            // 64-8+1
#define T2 50            // 57-8+1
#define FT (T1*H2C)      // 912 elems per node for xt (f16)
#define CAP 64           // fixed bucket capacity (P(deg>=64) ~ 1e-35)
#define GSTR 24          // gs row stride in halves (48 B: 16-B aligned rows)

typedef _Float16 half8 __attribute__((ext_vector_type(8)));
typedef _Float16 half4v __attribute__((ext_vector_type(4)));
typedef float f32x4 __attribute__((ext_vector_type(4)));

// ---------------------------------------------------------------------------
// Per-block int64-layout detection: first wave checks high words of the first
// 32 edge indices, ballot, LDS broadcast. ~32 L2-hot ints per block.
__device__ __forceinline__ int block_flag(const int* __restrict__ ei,
                                          int* sflag) {
    if (threadIdx.x < 64) {
        int bad = (threadIdx.x < 32) ? (ei[2 * threadIdx.x + 1] != 0) : 0;
        unsigned long long b = __ballot(bad);
        if (threadIdx.x == 0) *sflag = (b == 0ULL) ? 1 : 0;
    }
    __syncthreads();
    return *sflag;
}

__device__ __forceinline__ int load_row(const int* ei, int f, int e) {
    return f ? ei[2 * e] : ei[e];
}
__device__ __forceinline__ int load_col(const int* ei, int f, int e) {
    return f ? ei[2 * (EE + e)] : ei[EE + e];
}

// ---------------------------------------------------------------------------
// k_init: blocks 0..61 zero deg|cnt (contiguous 2*NN words, 62*256 = 15872
// exactly); blocks 62..161 do weight prep (25600 threads).
// w2p k-order (NEW): element e of a B-frag is (ci = g*4 + (e&3),
// tap = 2*s + (e>>2)) — taps grouped in halves so the gc2 A-frag is a plain
// concat of two 8-B LDS rows (no interleave shuffle). MFMA sums over k, so
// any A/B-consistent k-permutation is valid.
__global__ void k_init(float* __restrict__ deg,
                       const float* __restrict__ Wc2, _Float16* __restrict__ w2p,
                       const float* __restrict__ Wc1, _Float16* __restrict__ w1p,
                       const float* __restrict__ Wg, _Float16* __restrict__ wgp) {
    int b = blockIdx.x;
    if (b < 62) {
        // deg and cnt are contiguous in ws: zero both as one word range
        ((int*)deg)[b * 256 + threadIdx.x] = 0;
        return;
    }
    int i = (b - 62) * 256 + threadIdx.x;
    if (i < 16384) {
        // conv2 B-frags: slot=(s*4+lg)*128+nt*16+c, elem e (NEW k-order)
        int e = i & 7;
        int slot = i >> 3;
        int c  = slot & 15;
        int nt = (slot >> 4) & 7;
        int g  = (slot >> 7) & 3;
        int s  = (slot >> 9) & 3;
        int ci = g * 4 + (e & 3);
        w2p[i] = (_Float16)Wc2[(nt * 16 + c) * 128 + ci * 8 + 2 * s + (e >> 2)];
    } else if (i < 16384 + 8192) {
        // conv1 GEMM1 A-frags with sigma channel permutation
        int j = i - 16384;
        int e = j & 7;
        int m = (j >> 3) & 127;
        int slg = j >> 10;              // 0..7 = s*4+lg
        int ci = (slg >> 2) * 4 + (slg & 3);
        int hi = m >> 6;                // 0 = P, 1 = Q
        int mb = m & 63;
        int mt = mb >> 4, r = mb & 15;
        int sig = hi * 64 + 32 * (mt >> 1) + 8 * (r >> 2) + 4 * (mt & 1) + (r & 3);
        w1p[j] = (ci < CIN) ? (_Float16)Wc1[sig * (CIN * KK) + ci * KK + e]
                            : (_Float16)0.0f;
    } else if (i < 16384 + 8192 + 1024) {
        // conv1 GEMM2 B-frags (Wg)
        int j = i - 16384 - 8192;
        int e = j & 7;
        int f = (j >> 3) & 15;
        int slg = j >> 7;               // 0..7
        int c = (slg >> 2) * 32 + (slg & 3) * 8 + e;
        wgp[j] = (_Float16)Wg[c * H2C + f];
    }
}

// ---------------------------------------------------------------------------
// k_deg: single edge pass, ONE atomic per edge (the cnt atomic moved to the
// fill pass, which uses it as the bucket cursor).
__global__ void k_deg(const int* __restrict__ ei, const float* __restrict__ ew,
                      float* __restrict__ deg) {
    __shared__ int sflag;
    int f = block_flag(ei, &sflag);
    int e = blockIdx.x * 256 + threadIdx.x;
    int c = load_col(ei, f, e);
    atomicAdd(&deg[c], ew[e]);
}

// ---------------------------------------------------------------------------
// Merged kernel: blocks [0, NN/4) run conv1 (register-resident, wave = node);
// blocks [NN/4, NN/4+EE/256) run the edge bucket-fill into FIXED-CAPACITY
// buckets em[c*64+pos].
__global__ __launch_bounds__(256, 3) void k_conv1_fill(
        const float* __restrict__ x, const _Float16* __restrict__ w1p,
        const float* __restrict__ b1, const _Float16* __restrict__ wgp,
        _Float16* __restrict__ xt,
        const int* __restrict__ ei,
        const float* __restrict__ ew, const float* __restrict__ deg,
        int* __restrict__ cnt, int2* __restrict__ em) {
    if (blockIdx.x >= NN / 4) {
        // ---- bucket fill: em[c*64+pos] = (src, dinv[src]*ew) ----
        __shared__ int sflag;
        int f = block_flag(ei, &sflag);
        int e = (blockIdx.x - NN / 4) * 256 + threadIdx.x;
        if (e < EE) {
            int c = load_col(ei, f, e);
            int r = load_row(ei, f, e);
            int pos = atomicAdd(&cnt[c], 1);
            if (pos < CAP)
                em[(c << 6) + pos] =
                    make_int2(r, __float_as_int(rsqrtf(deg[r] + 1.0f) * ew[e]));
        }
        return;
    }
    // ---- conv1, fully register-resident (zero LDS, zero barriers) ----
    int tid = threadIdx.x;
    int w = tid >> 6, lane = tid & 63;
    int lc = lane & 15, lg = lane >> 4;
    int n = blockIdx.x * 4 + w;
    const float* xg = x + (size_t)n * (CIN * WW);

    const half8* w1v = (const half8*)w1p;
    const half8* wgv = (const half8*)wgp;

    half8 av[2][8];
#pragma unroll
    for (int s = 0; s < 2; ++s)
#pragma unroll
        for (int mt = 0; mt < 8; ++mt)
            av[s][mt] = w1v[(s * 4 + lg) * 128 + mt * 16 + lc];
    half8 bw[2];
#pragma unroll
    for (int s2 = 0; s2 < 2; ++s2) bw[s2] = wgv[(s2 * 4 + lg) * 16 + lc];

    const float* xr0 = xg + (size_t)lg * WW;
    const float* xr1 = xg + (size_t)(4 + lg) * WW;
    bool cok1 = (4 + lg) < CIN;

    f32x4 acc2[4];
#pragma unroll
    for (int mt2 = 0; mt2 < 4; ++mt2) acc2[mt2] = (f32x4)0.0f;

#pragma unroll
    for (int nt = 0; nt < 4; ++nt) {
        int t = nt * 16 + lc;
        half8 bf0, bf1;
#pragma unroll
        for (int e = 0; e < 8; ++e) {
            int tp = t + e;
            bf0[e] = (_Float16)((tp < WW) ? xr0[tp] : 0.0f);
            bf1[e] = (_Float16)((cok1 && tp < WW) ? xr1[tp] : 0.0f);
        }
        f32x4 acc[8];
#pragma unroll
        for (int mt = 0; mt < 8; ++mt) acc[mt] = (f32x4)0.0f;
#pragma unroll
        for (int mt = 0; mt < 8; ++mt)
            acc[mt] = __builtin_amdgcn_mfma_f32_16x16x32_f16(av[0][mt], bf0,
                                                             acc[mt], 0, 0, 0);
#pragma unroll
        for (int mt = 0; mt < 8; ++mt)
            acc[mt] = __builtin_amdgcn_mfma_f32_16x16x32_f16(av[1][mt], bf1,
                                                             acc[mt], 0, 0, 0);
        half4v h4[4];
#pragma unroll
        for (int mtp = 0; mtp < 4; ++mtp) {
            int cb = 32 * (mtp >> 1) + 8 * lg + 4 * (mtp & 1);
            float4 bP = *(const float4*)(b1 + cb);
            float4 bQ = *(const float4*)(b1 + 64 + cb);
            f32x4 P = acc[mtp];
            f32x4 Q = acc[mtp + 4];
            half4v hh;
            hh[0] = (_Float16)((P[0] + bP.x) * (1.0f / (1.0f + __expf(-(Q[0] + bQ.x)))));
            hh[1] = (_Float16)((P[1] + bP.y) * (1.0f / (1.0f + __expf(-(Q[1] + bQ.y)))));
            hh[2] = (_Float16)((P[2] + bP.z) * (1.0f / (1.0f + __expf(-(Q[2] + bQ.z)))));
            hh[3] = (_Float16)((P[3] + bP.w) * (1.0f / (1.0f + __expf(-(Q[3] + bQ.w)))));
            h4[mtp] = hh;
        }
#pragma unroll
        for (int s2 = 0; s2 < 2; ++s2) {
            half8 af = __builtin_shufflevector(h4[2 * s2], h4[2 * s2 + 1],
                                               0, 1, 2, 3, 4, 5, 6, 7);
            acc2[nt] = __builtin_amdgcn_mfma_f32_16x16x32_f16(af, bw[s2],
                                                              acc2[nt], 0, 0, 0);
        }
    }

    _Float16* xtn = xt + (size_t)n * FT;
#pragma unroll
    for (int mt2 = 0; mt2 < 4; ++mt2) {
#pragma unroll
        for (int j = 0; j < 4; ++j) {
            int t = mt2 * 16 + 4 * lg + j;
            if (t < T1) xtn[t * 16 + lc] = (_Float16)acc2[mt2][j];
        }
    }
}

// ---------------------------------------------------------------------------
// Fused gather + conv2. Wave = 1 node; gather loop byte-identical to the
// proven 88-µs version (2-deep pipeline, fixed-cap buckets, nt stores).
// NEW this round (epilogue only): gs stored [t][f] with 48-B padded rows.
//   - gather side: relu+bias output written as 2x ds_write_b128 per wave
//     (was 16 strided ds_write_u16),
//   - A-frags: concat of two 8-B ds_read_b64 rows (was 8 ds_read_u16 each;
//     128 -> 32 LDS reads/wave). k-order matched by the new w2p prep.
// Rows 57..70 of gs are read (for discarded out-rows t>=50) but never
// written: garbage values only affect discarded MFMA output rows, and all
// addresses stay inside the block's LDS allocation.
__global__ __launch_bounds__(256, 4) void k_gc2(
        const _Float16* __restrict__ xt, const float* __restrict__ deg,
        const int* __restrict__ cnt, const int2* __restrict__ em,
        const float* __restrict__ bg, const _Float16* __restrict__ w2p,
        const float* __restrict__ b2, float* __restrict__ out) {
    __shared__ __align__(16) _Float16 gs2[4][58 * GSTR];   // 2784 B per wave
    __shared__ __align__(16) float gout[4][16 * T2];       // 3200 B per wave
    int tid = threadIdx.x;
    int w = tid >> 6, lane = tid & 63;
    int lc = lane & 15, lg = lane >> 4;
    int n = blockIdx.x * 4 + w;
    bool hi = lane < 50;                // second half8 covers elems 512..911

    float dc = rsqrtf(deg[n] + 1.0f);
    float a0[8], a1[8];
    {
        const half8* xs = (const half8*)(xt + (size_t)n * FT);
        half8 u0 = xs[lane];
        half8 u1 = (half8)(_Float16)0.0f;
        if (hi) u1 = xs[64 + lane];
        float sw = dc * dc;
#pragma unroll
        for (int j = 0; j < 8; ++j) {
            a0[j] = (float)u0[j] * sw;
            a1[j] = (float)u1[j] * sw;
        }
    }
    int beg = n << 6;
    int m = min(cnt[n], CAP);
    int2 rw0 = make_int2(0, 0), rw1 = make_int2(0, 0);
    half8 c0 = (half8)(_Float16)0.0f, c1 = (half8)(_Float16)0.0f;
    if (m > 0) {
        rw0 = em[beg];
        const half8* xr = (const half8*)(xt + (size_t)rw0.x * FT);
        c0 = xr[lane];
        if (hi) c1 = xr[64 + lane];
    }
    if (m > 1) rw1 = em[beg + 1];
    for (int i = 0; i < m; ++i) {
        float wv = __int_as_float(rw0.y) * dc;
        half8 d0 = c0, d1 = c1;
        int2 rwn = (i + 2 < m) ? em[beg + i + 2] : rw1;
        if (i + 1 < m) {
            const half8* xr = (const half8*)(xt + (size_t)rw1.x * FT);
            c0 = xr[lane];
            c1 = (half8)(_Float16)0.0f;
            if (hi) c1 = xr[64 + lane];
        }
        rw0 = rw1; rw1 = rwn;
#pragma unroll
        for (int j = 0; j < 8; ++j) {
            a0[j] += (float)d0[j] * wv;
            a1[j] += (float)d1[j] * wv;
        }
    }

    // relu + bias -> gs2[t][f] (48-B rows). Lane owns f=(lane&1)*8..+8,
    // t = lane>>1 (a0) and 32+(lane>>1) (a1, lanes<50). Two b128 writes.
    {
        _Float16* g = gs2[w];
        int f0 = (lane & 1) * 8;
        int t0 = lane >> 1;
        float4 bgA = *(const float4*)(bg + f0);
        float4 bgB = *(const float4*)(bg + f0 + 4);
        float bv[8] = {bgA.x, bgA.y, bgA.z, bgA.w, bgB.x, bgB.y, bgB.z, bgB.w};
        half8 h0, h1;
#pragma unroll
        for (int j = 0; j < 8; ++j) {
            h0[j] = (_Float16)fmaxf(a0[j] + bv[j], 0.0f);
            h1[j] = (_Float16)fmaxf(a1[j] + bv[j], 0.0f);
        }
        *(half8*)(g + t0 * GSTR + f0) = h0;
        if (hi) *(half8*)(g + (32 + t0) * GSTR + f0) = h1;
    }
    // wave-private LDS region: compiler orders write->read via lgkmcnt,
    // no __syncthreads needed (waves fully independent).

    const _Float16* g = gs2[w];
    half8 af[4][4];
#pragma unroll
    for (int s = 0; s < 4; ++s)
#pragma unroll
        for (int mt = 0; mt < 4; ++mt) {
            int tb = mt * 16 + lc + 2 * s;
            half4v lo = *(const half4v*)(g + tb * GSTR + lg * 4);
            half4v hh = *(const half4v*)(g + (tb + 1) * GSTR + lg * 4);
            af[s][mt] = __builtin_shufflevector(lo, hh, 0, 1, 2, 3, 4, 5, 6, 7);
        }

    const half8* wsv = (const half8*)w2p;
    float* outn = out + (size_t)n * (H1C * T2);
    float* go = gout[w];
#pragma unroll
    for (int ntp = 0; ntp < 4; ++ntp) {
        f32x4 aP[4], aQ[4];
#pragma unroll
        for (int mt = 0; mt < 4; ++mt) { aP[mt] = (f32x4)0.0f; aQ[mt] = (f32x4)0.0f; }
#pragma unroll
        for (int s = 0; s < 4; ++s) {
            half8 bP = wsv[(s * 4 + lg) * 128 + ntp * 16 + lc];
            half8 bQ = wsv[(s * 4 + lg) * 128 + (ntp + 4) * 16 + lc];
#pragma unroll
            for (int mt = 0; mt < 4; ++mt) {
                aP[mt] = __builtin_amdgcn_mfma_f32_16x16x32_f16(af[s][mt], bP,
                                                                aP[mt], 0, 0, 0);
                aQ[mt] = __builtin_amdgcn_mfma_f32_16x16x32_f16(af[s][mt], bQ,
                                                                aQ[mt], 0, 0, 0);
            }
        }
        int c = ntp * 16 + lc;
        float bp = b2[c], bq = b2[64 + c];
        // stage [lc][t<50] into wave-private LDS (column-major rows of 50)
#pragma unroll
        for (int mt = 0; mt < 4; ++mt) {
#pragma unroll
            for (int e2 = 0; e2 < 4; ++e2) {
                int t = mt * 16 + lg * 4 + e2;
                if (t < T2) {
                    float vv = (aP[mt][e2] + bp) *
                               (1.0f / (1.0f + __expf(-(aQ[mt][e2] + bq))));
                    go[lc * T2 + t] = vv;
                }
            }
        }
        // coalesced nontemporal writeback: 800 floats = 3x1024B + 128B
        float* dst = outn + ntp * (16 * T2);
#pragma unroll
        for (int i = 0; i < 3; ++i) {
            f32x4 v = *(const f32x4*)(go + i * 256 + lane * 4);
            __builtin_nontemporal_store(v, (f32x4*)(dst + i * 256 + lane * 4));
        }
        if (lane < 8) {
            f32x4 v = *(const f32x4*)(go + 768 + lane * 4);
            __builtin_nontemporal_store(v, (f32x4*)(dst + 768 + lane * 4));
        }
    }
}

// ---------------------------------------------------------------------------
extern "C" void kernel_launch(void* const* d_in, const int* in_sizes, int n_in,
                              void* d_out, int out_size, void* d_ws, size_t ws_size,
                              hipStream_t stream) {
    const float* x   = (const float*)d_in[0];
    const int*   ei  = (const int*)d_in[1];
    const float* ea  = (const float*)d_in[2];
    const float* Wc1 = (const float*)d_in[4];
    const float* b1  = (const float*)d_in[5];
    const float* Wg  = (const float*)d_in[6];
    const float* bg  = (const float*)d_in[7];
    const float* Wc2 = (const float*)d_in[8];
    const float* b2  = (const float*)d_in[9];
    float* out = (float*)d_out;

    char* ws = (char*)d_ws;
    size_t off = 0;
    auto alloc = [&](size_t bytes) -> void* {
        void* p = ws + off;
        off += (bytes + 255) & ~(size_t)255;
        return p;
    };
    // deg | cnt contiguous -> k_init zeroes both as one 2*NN word range
    float*    deg = (float*)alloc((size_t)NN * 4);      // 31744
    int*      cnt = (int*)alloc((size_t)NN * 4);        // 31744
    int2*     em  = (int2*)alloc((size_t)NN * CAP * 8); // 4.06 MB fixed-cap
    _Float16* xt  = (_Float16*)alloc((size_t)NN * FT * 2);
    _Float16* w2p = (_Float16*)alloc((size_t)16384 * 2);
    _Float16* w1p = (_Float16*)alloc((size_t)8192 * 2);
    _Float16* wgp = (_Float16*)alloc((size_t)1024 * 2);
    (void)ws_size; (void)in_sizes; (void)n_in; (void)out_size;

    k_init<<<162, 256, 0, stream>>>(deg, Wc2, w2p, Wc1, w1p, Wg, wgp);
    k_deg<<<EE / 256, 256, 0, stream>>>(ei, ea, deg);
    k_conv1_fill<<<NN / 4 + EE / 256, 256, 0, stream>>>(x, w1p, b1, wgp, xt,
                                                        ei, ea, deg, cnt, em);
    k_gc2<<<NN / 4, 256, 0, stream>>>(xt, deg, cnt, em, bg, w2p, b2, out);
}